// Round 7
// baseline (3797.493 us; speedup 1.0000x reference)
//
#include <hip/hip_runtime.h>

// BlockSparseLinear: out[M,N] = 2 * (x[M,K] @ (W .* mask)^T) + bias[N]
// M = 16384, N = 4096, K = 4096, mask 32x32 blocks over (128,128).
// v7 = v6 (256x256 tile, BK=32, 8 waves 2Mx4N, pre-swizzled bf16 operands,
// B-staging redirect skip, SGPR-bitmask MFMA skip, XCD swizzle) with the
// LDS ring cut to 2 slots (64 KiB total) so TWO blocks co-reside per CU
// (16 waves/CU): the partner block covers barrier/LDS-latency stalls that
// bound v4/v6 at 1 block/CU. Pipeline is depth-1 but counted: per tile,
// barrier -> stage(t+1) -> vmcnt(4) (stage(t) landed, stage(t+1) in
// flight; drain-0 only on the final tile) -> barrier -> compute.

typedef short s16x8 __attribute__((ext_vector_type(8)));
typedef float f32x4 __attribute__((ext_vector_type(4)));
typedef unsigned short u16;
typedef unsigned long long u64;

#define M_TOT 16384
#define N_TOT 4096
#define K_TOT 4096
#define MASK_DIM 128
#define NT 128         // K tiles of 32
#define LDS_STRIDE 72  // legacy fallback kernel only

__device__ __forceinline__ u16 f2bf(float f) {
  union { float f; unsigned u; } v; v.f = f;
  unsigned r = v.u + 0x7FFFu + ((v.u >> 16) & 1u);  // round-to-nearest-even
  return (u16)(r >> 16);
}

__device__ __forceinline__ void load16_to_lds(const u16* g, u16* l) {
  __builtin_amdgcn_global_load_lds(
      (const __attribute__((address_space(1))) void*)g,
      (__attribute__((address_space(3))) void*)l, 16, 0, 0);
}

// ---------------------------------------------------------------------------
// Mask normalization (format auto-detect) + bit-pack (maskbits[row][4] u32).
// ---------------------------------------------------------------------------
__global__ void prep_mask_kernel(const unsigned char* __restrict__ m,
                                 unsigned char* __restrict__ outm,
                                 unsigned* __restrict__ outbits) {
  __shared__ int s_ok[4];
  const int t = threadIdx.x;
  unsigned v = reinterpret_cast<const unsigned*>(m)[t];
  bool wordlike = (v <= 1u) || (v == 0x3F800000u);
  unsigned long long b = __ballot(wordlike);
  if ((t & 63) == 0) s_ok[t >> 6] = (b == ~0ull) ? 1 : 0;
  __syncthreads();
  const bool word_fmt = s_ok[0] && s_ok[1] && s_ok[2] && s_ok[3];
  for (int i = t; i < MASK_DIM * MASK_DIM; i += 256) {
    bool nz = word_fmt ? (reinterpret_cast<const unsigned*>(m)[i] != 0u)
                       : (m[i] != 0);
    outm[i] = nz ? 1 : 0;
  }
  __syncthreads();
  for (int i = t; i < MASK_DIM * 4; i += 256) {
    const int r = i >> 2, w = i & 3;
    unsigned acc = 0;
    for (int bit = 0; bit < 32; ++bit)
      acc |= (unsigned)(outm[r * MASK_DIM + w * 32 + bit] != 0) << bit;
    outbits[i] = acc;
  }
}

// ---------------------------------------------------------------------------
// x fp32 [M][K] -> bf16, pre-swizzled: within each 32-elem K-tile (64B), 16B
// chunk c goes to slot c ^ ((row>>1)&3).
// ---------------------------------------------------------------------------
__global__ void prep_x_swz_kernel(const float* __restrict__ x,
                                  u16* __restrict__ xb) {
  const size_t t = (size_t)blockIdx.x * 256 + threadIdx.x;  // 16B-chunk index
  const size_t row = t >> 9;        // 512 chunks per 4096-elem row
  const int wc = (int)(t & 511);
  const int blk = wc >> 2;          // K-tile 0..127
  const int c = wc & 3;             // chunk within tile
  const float4 v0 = *reinterpret_cast<const float4*>(x + row * K_TOT + wc * 8);
  const float4 v1 = *reinterpret_cast<const float4*>(x + row * K_TOT + wc * 8 + 4);
  s16x8 b;
  b[0] = (short)f2bf(v0.x); b[1] = (short)f2bf(v0.y);
  b[2] = (short)f2bf(v0.z); b[3] = (short)f2bf(v0.w);
  b[4] = (short)f2bf(v1.x); b[5] = (short)f2bf(v1.y);
  b[6] = (short)f2bf(v1.z); b[7] = (short)f2bf(v1.w);
  *reinterpret_cast<s16x8*>(xb + row * K_TOT + blk * 32 +
                            (size_t)((c ^ (((int)row >> 1) & 3)) * 8)) = b;
}

// ---------------------------------------------------------------------------
// W fp32 [N][K] -> masked bf16, pre-swizzled (same scheme).
// ---------------------------------------------------------------------------
__global__ void prep_w_swz_kernel(const float* __restrict__ w,
                                  const unsigned char* __restrict__ mask8,
                                  u16* __restrict__ wb) {
  const size_t t = (size_t)blockIdx.x * 256 + threadIdx.x;
  const size_t row = t >> 9;
  const int wc = (int)(t & 511);
  const int blk = wc >> 2;
  const int c = wc & 3;
  s16x8 b = {};
  if (mask8[((int)row >> 5) * MASK_DIM + blk]) {
    const float4 v0 = *reinterpret_cast<const float4*>(w + row * K_TOT + wc * 8);
    const float4 v1 = *reinterpret_cast<const float4*>(w + row * K_TOT + wc * 8 + 4);
    b[0] = (short)f2bf(v0.x); b[1] = (short)f2bf(v0.y);
    b[2] = (short)f2bf(v0.z); b[3] = (short)f2bf(v0.w);
    b[4] = (short)f2bf(v1.x); b[5] = (short)f2bf(v1.y);
    b[6] = (short)f2bf(v1.z); b[7] = (short)f2bf(v1.w);
  }
  *reinterpret_cast<s16x8*>(wb + row * K_TOT + blk * 32 +
                            (size_t)((c ^ (((int)row >> 1) & 3)) * 8)) = b;
}

// ---------------------------------------------------------------------------
// Legacy linear prep_w (for the ws-fits-W-only fallback path).
// ---------------------------------------------------------------------------
__global__ void prep_w_kernel(const float* __restrict__ w,
                              const unsigned char* __restrict__ mask8,
                              u16* __restrict__ wb) {
  const size_t e = ((size_t)blockIdx.x * blockDim.x + threadIdx.x) * 4;
  const int n = (int)(e >> 12);
  const int k = (int)(e & 4095);
  const float4 v = *reinterpret_cast<const float4*>(w + e);
  ushort4 bvec;
  if (mask8[(n >> 5) * MASK_DIM + (k >> 5)]) {
    bvec.x = f2bf(v.x); bvec.y = f2bf(v.y); bvec.z = f2bf(v.z); bvec.w = f2bf(v.w);
  } else {
    bvec.x = 0; bvec.y = 0; bvec.z = 0; bvec.w = 0;
  }
  *reinterpret_cast<ushort4*>(wb + e) = bvec;
}

// ---------------------------------------------------------------------------
// v7 GEMM: 256x256, BK=32, 2-slot LDS (64 KiB -> 2 blocks/CU), counted
// vmcnt(4), B-stage redirect skip, SGPR-bitmask MFMA skip.
// C = 2 * A @ B^T + bias.
// ---------------------------------------------------------------------------
__global__ __launch_bounds__(512, 4) void gemm8_kernel(
    const u16* __restrict__ xb, const u16* __restrict__ wb,
    const unsigned* __restrict__ maskbits,
    const float* __restrict__ bias, float* __restrict__ out) {
  extern __shared__ __align__(16) u16 lds[];  // A[2][256][32] | B[2][256][32]

  const int tid = threadIdx.x;
  const int lane = tid & 63;
  const int w = tid >> 6;
  const int wr = w >> 2;   // 0..1: rows [wr*128, +128)
  const int wc = w & 3;    // 0..3: cols [wc*64, +64)
  const int lrow = lane & 15;
  const int g = lane >> 4;
  const int kphys = ((g ^ ((lrow >> 1) & 3)) << 4);  // physical 16B chunk byte

  // XCD-aware bijective swizzle (grid = 1024, divisible by 8).
  int id = blockIdx.x;
  id = (id & 7) * (gridDim.x >> 3) + (id >> 3);
  const int bm = (id >> 4) << 8;  // 64 m-tiles
  const int bn = (id & 15) << 8;  // 16 n-tiles

  const char* ldsb = (const char*)lds;

  // ---- wave-uniform mask bits in SGPRs -----------------------------------
  const unsigned* cp = maskbits + (((bn >> 5) + wc * 2) << 2);
  const u64 m0lo = (u64)__builtin_amdgcn_readfirstlane(cp[0]) |
                   ((u64)__builtin_amdgcn_readfirstlane(cp[1]) << 32);
  const u64 m0hi = (u64)__builtin_amdgcn_readfirstlane(cp[2]) |
                   ((u64)__builtin_amdgcn_readfirstlane(cp[3]) << 32);
  const u64 m1lo = (u64)__builtin_amdgcn_readfirstlane(cp[4]) |
                   ((u64)__builtin_amdgcn_readfirstlane(cp[5]) << 32);
  const u64 m1hi = (u64)__builtin_amdgcn_readfirstlane(cp[6]) |
                   ((u64)__builtin_amdgcn_readfirstlane(cp[7]) << 32);
  // Staging bits: wave w stages B rows [w*16,+16) (op0) and +128 (op1).
  const unsigned* sp0 = maskbits + (((bn >> 5) + (w >> 1)) << 2);
  const unsigned* sp1 = maskbits + (((bn >> 5) + 4 + (w >> 1)) << 2);
  const u64 sg0lo = (u64)__builtin_amdgcn_readfirstlane(sp0[0]) |
                    ((u64)__builtin_amdgcn_readfirstlane(sp0[1]) << 32);
  const u64 sg0hi = (u64)__builtin_amdgcn_readfirstlane(sp0[2]) |
                    ((u64)__builtin_amdgcn_readfirstlane(sp0[3]) << 32);
  const u64 sg1lo = (u64)__builtin_amdgcn_readfirstlane(sp1[0]) |
                    ((u64)__builtin_amdgcn_readfirstlane(sp1[1]) << 32);
  const u64 sg1hi = (u64)__builtin_amdgcn_readfirstlane(sp1[2]) |
                    ((u64)__builtin_amdgcn_readfirstlane(sp1[3]) << 32);

  // Staging geometry: thread -> row tid>>2, 16B chunk tid&3.
  const int sr = tid >> 2;
  const int sc8 = (tid & 3) * 8;
  const u16* gaBase = xb + (size_t)(bm + sr) * K_TOT + sc8;
  const u16* ga2Base = gaBase + (size_t)128 * K_TOT;
  const u16* gb0Base = wb + (size_t)(bn + sr) * K_TOT + sc8;
  const u16* gb1Base = gb0Base + (size_t)128 * K_TOT;

  f32x4 acc[8][4] = {};

  auto stage = [&](int t) {
    const int s = t & 1;
    const int k0 = t << 5;
    const int sh = t & 63;
    const u64 s0 = (t & 64) ? sg0hi : sg0lo;
    const u64 s1 = (t & 64) ? sg1hi : sg1lo;
    const u16* ga = gaBase + k0;
    const u16* ga2 = ga2Base + k0;
    // Redirect skipped B loads to the A source (L1-hit dummy): op count and
    // LDS-dest layout stay fixed, so counted vmcnt remains valid.
    const u16* gb0 = ((int)((s0 >> sh) & 1)) ? gb0Base + k0 : ga;
    const u16* gb1 = ((int)((s1 >> sh) & 1)) ? gb1Base + k0 : ga2;
    u16* la = lds + s * 8192 + w * 512;            // wave-uniform dest base
    u16* lb = lds + 16384 + s * 8192 + w * 512;
    load16_to_lds(ga, la);
    load16_to_lds(ga2, la + 4096);
    load16_to_lds(gb0, lb);
    load16_to_lds(gb1, lb + 4096);
  };

  // Prologue: stage tile 0 (4 ops in flight).
  stage(0);

#define TILE(t, VMSTR)                                                        \
  {                                                                           \
    const int s_ = (t) & 1;                                                   \
    const int abase = s_ * 16384;                                             \
    const int bbase = 32768 + s_ * 16384;                                     \
    __builtin_amdgcn_s_barrier();  /* slot (t+1)&1 readers (tile t-1) done */ \
    if ((t) + 1 < NT) stage((t) + 1);                                         \
    asm volatile("s_waitcnt " VMSTR ::: "memory"); /* stage(t) landed */      \
    __builtin_amdgcn_s_barrier();  /* all waves' stage(t) landed */           \
    const int sh = (t) & 63;                                                  \
    const u64 sel0 = ((t) & 64) ? m0hi : m0lo;                                \
    const u64 sel1 = ((t) & 64) ? m1hi : m1lo;                                \
    const int b0 = (int)((sel0 >> sh) & 1);                                   \
    const int b1 = (int)((sel1 >> sh) & 1);                                   \
    if (b0 | b1) {                                                            \
      s16x8 af[8];                                                            \
      _Pragma("unroll") for (int m = 0; m < 8; ++m)                           \
          af[m] = *(const s16x8*)(ldsb + abase +                              \
                                  (wr * 128 + m * 16 + lrow) * 64 + kphys);   \
      s16x8 bfv[4];                                                           \
      if (b0) {                                                               \
        bfv[0] = *(const s16x8*)(ldsb + bbase +                               \
                                 (wc * 64 + 0 * 16 + lrow) * 64 + kphys);     \
        bfv[1] = *(const s16x8*)(ldsb + bbase +                               \
                                 (wc * 64 + 1 * 16 + lrow) * 64 + kphys);     \
      }                                                                       \
      if (b1) {                                                               \
        bfv[2] = *(const s16x8*)(ldsb + bbase +                               \
                                 (wc * 64 + 2 * 16 + lrow) * 64 + kphys);     \
        bfv[3] = *(const s16x8*)(ldsb + bbase +                               \
                                 (wc * 64 + 3 * 16 + lrow) * 64 + kphys);     \
      }                                                                       \
      asm volatile("s_waitcnt lgkmcnt(0)" ::: "memory");                      \
      __builtin_amdgcn_sched_barrier(0);                                      \
      __builtin_amdgcn_s_setprio(1);                                          \
      if (b0) {                                                               \
        _Pragma("unroll") for (int m = 0; m < 8; ++m) {                       \
          acc[m][0] = __builtin_amdgcn_mfma_f32_16x16x32_bf16(                \
              af[m], bfv[0], acc[m][0], 0, 0, 0);                             \
          acc[m][1] = __builtin_amdgcn_mfma_f32_16x16x32_bf16(                \
              af[m], bfv[1], acc[m][1], 0, 0, 0);                             \
        }                                                                     \
      }                                                                       \
      if (b1) {                                                               \
        _Pragma("unroll") for (int m = 0; m < 8; ++m) {                       \
          acc[m][2] = __builtin_amdgcn_mfma_f32_16x16x32_bf16(                \
              af[m], bfv[2], acc[m][2], 0, 0, 0);                             \
          acc[m][3] = __builtin_amdgcn_mfma_f32_16x16x32_bf16(                \
              af[m], bfv[3], acc[m][3], 0, 0, 0);                             \
        }                                                                     \
      }                                                                       \
      __builtin_amdgcn_s_setprio(0);                                          \
    }                                                                         \
  }

  for (int t = 0; t < NT - 1; ++t) TILE(t, "vmcnt(4)");
  TILE(NT - 1, "vmcnt(0)");
#undef TILE

  // Epilogue: out = 2*acc + bias. C/D frag: col = lane&15, row = g*4 + j.
#pragma unroll
  for (int n = 0; n < 4; ++n) {
    const int gcol = bn + wc * 64 + n * 16 + lrow;
    const float bv = bias[gcol];
#pragma unroll
    for (int m = 0; m < 8; ++m) {
      const int grow = bm + wr * 128 + m * 16 + (g << 2);
#pragma unroll
      for (int j = 0; j < 4; ++j)
        out[(size_t)(grow + j) * N_TOT + gcol] = 2.0f * acc[m][n][j] + bv;
    }
  }
}

// ---------------------------------------------------------------------------
// Legacy reg-staged GEMM (fallback when ws can't hold xb).
// ---------------------------------------------------------------------------
template <bool PREPPED>
__global__ __launch_bounds__(256) void gemm_kernel(
    const float* __restrict__ x, const u16* __restrict__ wb,
    const float* __restrict__ wf, const unsigned char* __restrict__ mask8,
    const float* __restrict__ bias, float* __restrict__ out) {
  __shared__ __align__(16) u16 Asl[128 * LDS_STRIDE];
  __shared__ __align__(16) u16 Bsl[128 * LDS_STRIDE];

  const int tid = threadIdx.x;
  const int lane = tid & 63;
  const int wave = tid >> 6;
  const int wr = wave >> 1;
  const int wcn = wave & 1;

  int id = blockIdx.x;
  const int cpx = gridDim.x >> 3;
  id = (id & 7) * cpx + (id >> 3);
  const int bm = (id >> 5) << 7;
  const int bn = (id & 31) << 7;

  const int arow = tid >> 4;
  const int acol = (tid & 15) << 2;
  const int brow = tid >> 3;
  const int bcol = (tid & 7) << 3;

  const int lrow = lane & 15;
  const int lgo = (lane >> 4) << 3;

  f32x4 acc[4][4] = {};

  for (int k0 = 0; k0 < K_TOT; k0 += 64) {
#pragma unroll
    for (int r = 0; r < 8; ++r) {
      const int row = arow + r * 16;
      const float4 v = *reinterpret_cast<const float4*>(
          x + (size_t)(bm + row) * K_TOT + k0 + acol);
      ushort4 bvec;
      bvec.x = f2bf(v.x); bvec.y = f2bf(v.y); bvec.z = f2bf(v.z); bvec.w = f2bf(v.w);
      *reinterpret_cast<ushort4*>(&Asl[row * LDS_STRIDE + acol]) = bvec;
    }
    if (PREPPED) {
#pragma unroll
      for (int r = 0; r < 4; ++r) {
        const int row = brow + r * 32;
        const s16x8 v = *reinterpret_cast<const s16x8*>(
            wb + (size_t)(bn + row) * K_TOT + k0 + bcol);
        *reinterpret_cast<s16x8*>(&Bsl[row * LDS_STRIDE + bcol]) = v;
      }
    } else {
#pragma unroll
      for (int r = 0; r < 8; ++r) {
        const int row = arow + r * 16;
        const float4 v = *reinterpret_cast<const float4*>(
            wf + (size_t)(bn + row) * K_TOT + k0 + acol);
        ushort4 bvec;
        bvec.x = 0; bvec.y = 0; bvec.z = 0; bvec.w = 0;
        if (mask8[((bn + row) >> 5) * MASK_DIM + ((k0 + acol) >> 5)]) {
          bvec.x = f2bf(v.x); bvec.y = f2bf(v.y); bvec.z = f2bf(v.z); bvec.w = f2bf(v.w);
        }
        *reinterpret_cast<ushort4*>(&Bsl[row * LDS_STRIDE + acol]) = bvec;
      }
    }
    __syncthreads();

#pragma unroll
    for (int ks = 0; ks < 2; ++ks) {
      s16x8 af[4], bfv[4];
#pragma unroll
      for (int m = 0; m < 4; ++m)
        af[m] = *reinterpret_cast<const s16x8*>(
            &Asl[(wr * 64 + m * 16 + lrow) * LDS_STRIDE + ks * 32 + lgo]);
#pragma unroll
      for (int n = 0; n < 4; ++n)
        bfv[n] = *reinterpret_cast<const s16x8*>(
            &Bsl[(wcn * 64 + n * 16 + lrow) * LDS_STRIDE + ks * 32 + lgo]);
#pragma unroll
      for (int m = 0; m < 4; ++m)
#pragma unroll
        for (int n = 0; n < 4; ++n)
          acc[m][n] = __builtin_amdgcn_mfma_f32_16x16x32_bf16(af[m], bfv[n],
                                                              acc[m][n], 0, 0, 0);
    }
    __syncthreads();
  }

#pragma unroll
  for (int n = 0; n < 4; ++n) {
    const int gcol = bn + wcn * 64 + n * 16 + lrow;
    const float bv = bias[gcol];
#pragma unroll
    for (int m = 0; m < 4; ++m) {
      const int grow = bm + wr * 64 + m * 16 + ((lane >> 4) << 2);
#pragma unroll
      for (int j = 0; j < 4; ++j) {
        out[(size_t)(grow + j) * N_TOT + gcol] = 2.0f * acc[m][n][j] + bv;
      }
    }
  }
}

extern "C" void kernel_launch(void* const* d_in, const int* in_sizes, int n_in,
                              void* d_out, int out_size, void* d_ws, size_t ws_size,
                              hipStream_t stream) {
  const float* x = (const float*)d_in[0];
  const float* w = (const float*)d_in[1];
  const float* bias = (const float*)d_in[2];
  const unsigned char* mask_raw = (const unsigned char*)d_in[3];
  float* out = (float*)d_out;

  unsigned char* ws_mask = (unsigned char*)d_ws;            // 16 KiB mask8
  unsigned* ws_bits = (unsigned*)((char*)d_ws + 16384);     // 2 KiB bitmask
  u16* wb = (u16*)((char*)d_ws + 65536);                    // 32 MiB bf16 W
  u16* xb = (u16*)((char*)d_ws + 65536 +
                   (size_t)N_TOT * K_TOT * sizeof(u16));    // 128 MiB bf16 x
  const size_t need_w = 65536 + (size_t)N_TOT * K_TOT * sizeof(u16);
  const size_t need_full = need_w + (size_t)M_TOT * K_TOT * sizeof(u16);

  prep_mask_kernel<<<1, 256, 0, stream>>>(mask_raw, ws_mask, ws_bits);

  if (ws_size >= need_full) {
    prep_w_swz_kernel<<<(N_TOT * (K_TOT / 8)) / 256, 256, 0, stream>>>(w, ws_mask, wb);
    prep_x_swz_kernel<<<(M_TOT * (K_TOT / 8)) / 256, 256, 0, stream>>>(x, xb);
    hipFuncSetAttribute(reinterpret_cast<const void*>(gemm8_kernel),
                        hipFuncAttributeMaxDynamicSharedMemorySize, 65536);
    gemm8_kernel<<<(M_TOT / 256) * (N_TOT / 256), 512, 65536, stream>>>(
        xb, wb, ws_bits, bias, out);
  } else if (ws_size >= need_w) {
    prep_w_kernel<<<(N_TOT * K_TOT) / (256 * 4), 256, 0, stream>>>(w, ws_mask, wb);
    gemm_kernel<true><<<(M_TOT / 128) * (N_TOT / 128), 256, 0, stream>>>(
        x, wb, nullptr, nullptr, bias, out);
  } else {
    gemm_kernel<false><<<(M_TOT / 128) * (N_TOT / 128), 256, 0, stream>>>(
        x, nullptr, w, ws_mask, bias, out);
  }
}

// Round 8
// 672.190 us; speedup vs baseline: 5.6494x; 5.6494x over previous
//
#include <hip/hip_runtime.h>

// BlockSparseLinear: out[M,N] = 2 * (x[M,K] @ (W .* mask)^T) + bias[N]
// M = 16384, N = 4096, K = 4096, mask 32x32 blocks over (128,128).
// v8: two INDEPENDENT blocks per CU without spills.
//   tile 128x256, 8 waves of 64x64 (acc[4][4]=64 regs; unified live set
//   ~120 <= 128 budget at 4 waves/SIMD), LDS 2 slots x 24 KiB = 48 KiB
//   static -> 2 blocks/CU (distinct barrier domains cover each other's
//   barrier/lgkm stalls). Counted depth-1 ring: per tile
//   barrier -> stage(t+1) (3 ops) -> vmcnt(3) -> barrier -> compute.
//   B-staging redirect skip + SGPR-bitmask MFMA skip, pre-swizzled bf16
//   operands in d_ws, XCD-bijective block swizzle (grid 2048).

typedef short s16x8 __attribute__((ext_vector_type(8)));
typedef float f32x4 __attribute__((ext_vector_type(4)));
typedef unsigned short u16;
typedef unsigned long long u64;

#define M_TOT 16384
#define N_TOT 4096
#define K_TOT 4096
#define MASK_DIM 128
#define NT 128         // K tiles of 32
#define LDS_STRIDE 72  // legacy fallback kernel only

__device__ __forceinline__ u16 f2bf(float f) {
  union { float f; unsigned u; } v; v.f = f;
  unsigned r = v.u + 0x7FFFu + ((v.u >> 16) & 1u);  // round-to-nearest-even
  return (u16)(r >> 16);
}

__device__ __forceinline__ void load16_to_lds(const u16* g, u16* l) {
  __builtin_amdgcn_global_load_lds(
      (const __attribute__((address_space(1))) void*)g,
      (__attribute__((address_space(3))) void*)l, 16, 0, 0);
}

// ---------------------------------------------------------------------------
// Mask normalization (format auto-detect) + bit-pack (maskbits[row][4] u32).
// ---------------------------------------------------------------------------
__global__ void prep_mask_kernel(const unsigned char* __restrict__ m,
                                 unsigned char* __restrict__ outm,
                                 unsigned* __restrict__ outbits) {
  __shared__ int s_ok[4];
  const int t = threadIdx.x;
  unsigned v = reinterpret_cast<const unsigned*>(m)[t];
  bool wordlike = (v <= 1u) || (v == 0x3F800000u);
  unsigned long long b = __ballot(wordlike);
  if ((t & 63) == 0) s_ok[t >> 6] = (b == ~0ull) ? 1 : 0;
  __syncthreads();
  const bool word_fmt = s_ok[0] && s_ok[1] && s_ok[2] && s_ok[3];
  for (int i = t; i < MASK_DIM * MASK_DIM; i += 256) {
    bool nz = word_fmt ? (reinterpret_cast<const unsigned*>(m)[i] != 0u)
                       : (m[i] != 0);
    outm[i] = nz ? 1 : 0;
  }
  __syncthreads();
  for (int i = t; i < MASK_DIM * 4; i += 256) {
    const int r = i >> 2, w = i & 3;
    unsigned acc = 0;
    for (int bit = 0; bit < 32; ++bit)
      acc |= (unsigned)(outm[r * MASK_DIM + w * 32 + bit] != 0) << bit;
    outbits[i] = acc;
  }
}

// ---------------------------------------------------------------------------
// x fp32 [M][K] -> bf16, pre-swizzled: within each 32-elem K-tile (64B), 16B
// chunk c goes to slot c ^ ((row>>1)&3).
// ---------------------------------------------------------------------------
__global__ void prep_x_swz_kernel(const float* __restrict__ x,
                                  u16* __restrict__ xb) {
  const size_t t = (size_t)blockIdx.x * 256 + threadIdx.x;  // 16B-chunk index
  const size_t row = t >> 9;        // 512 chunks per 4096-elem row
  const int wc = (int)(t & 511);
  const int blk = wc >> 2;          // K-tile 0..127
  const int c = wc & 3;             // chunk within tile
  const float4 v0 = *reinterpret_cast<const float4*>(x + row * K_TOT + wc * 8);
  const float4 v1 = *reinterpret_cast<const float4*>(x + row * K_TOT + wc * 8 + 4);
  s16x8 b;
  b[0] = (short)f2bf(v0.x); b[1] = (short)f2bf(v0.y);
  b[2] = (short)f2bf(v0.z); b[3] = (short)f2bf(v0.w);
  b[4] = (short)f2bf(v1.x); b[5] = (short)f2bf(v1.y);
  b[6] = (short)f2bf(v1.z); b[7] = (short)f2bf(v1.w);
  *reinterpret_cast<s16x8*>(xb + row * K_TOT + blk * 32 +
                            (size_t)((c ^ (((int)row >> 1) & 3)) * 8)) = b;
}

// ---------------------------------------------------------------------------
// W fp32 [N][K] -> masked bf16, pre-swizzled (same scheme).
// ---------------------------------------------------------------------------
__global__ void prep_w_swz_kernel(const float* __restrict__ w,
                                  const unsigned char* __restrict__ mask8,
                                  u16* __restrict__ wb) {
  const size_t t = (size_t)blockIdx.x * 256 + threadIdx.x;
  const size_t row = t >> 9;
  const int wc = (int)(t & 511);
  const int blk = wc >> 2;
  const int c = wc & 3;
  s16x8 b = {};
  if (mask8[((int)row >> 5) * MASK_DIM + blk]) {
    const float4 v0 = *reinterpret_cast<const float4*>(w + row * K_TOT + wc * 8);
    const float4 v1 = *reinterpret_cast<const float4*>(w + row * K_TOT + wc * 8 + 4);
    b[0] = (short)f2bf(v0.x); b[1] = (short)f2bf(v0.y);
    b[2] = (short)f2bf(v0.z); b[3] = (short)f2bf(v0.w);
    b[4] = (short)f2bf(v1.x); b[5] = (short)f2bf(v1.y);
    b[6] = (short)f2bf(v1.z); b[7] = (short)f2bf(v1.w);
  }
  *reinterpret_cast<s16x8*>(wb + row * K_TOT + blk * 32 +
                            (size_t)((c ^ (((int)row >> 1) & 3)) * 8)) = b;
}

// ---------------------------------------------------------------------------
// Legacy linear prep_w (for the ws-fits-W-only fallback path).
// ---------------------------------------------------------------------------
__global__ void prep_w_kernel(const float* __restrict__ w,
                              const unsigned char* __restrict__ mask8,
                              u16* __restrict__ wb) {
  const size_t e = ((size_t)blockIdx.x * blockDim.x + threadIdx.x) * 4;
  const int n = (int)(e >> 12);
  const int k = (int)(e & 4095);
  const float4 v = *reinterpret_cast<const float4*>(w + e);
  ushort4 bvec;
  if (mask8[(n >> 5) * MASK_DIM + (k >> 5)]) {
    bvec.x = f2bf(v.x); bvec.y = f2bf(v.y); bvec.z = f2bf(v.z); bvec.w = f2bf(v.w);
  } else {
    bvec.x = 0; bvec.y = 0; bvec.z = 0; bvec.w = 0;
  }
  *reinterpret_cast<ushort4*>(wb + e) = bvec;
}

// ---------------------------------------------------------------------------
// v8 GEMM: 128x256 tile, 8 waves of 64x64, BK=32, 2-slot ring (48 KiB),
// counted vmcnt(3), redirect skip + bitmask MFMA skip.
// C = 2 * A @ B^T + bias.
// ---------------------------------------------------------------------------
__global__ __launch_bounds__(512, 4) void gemm_v8_kernel(
    const u16* __restrict__ xb, const u16* __restrict__ wb,
    const unsigned* __restrict__ maskbits,
    const float* __restrict__ bias, float* __restrict__ out) {
  __shared__ __align__(16) u16 As[2 * 4096];   // 2 slots x 128 rows x 32
  __shared__ __align__(16) u16 Bs[2 * 8192];   // 2 slots x 256 rows x 32

  const int tid = threadIdx.x;
  const int lane = tid & 63;
  const int w = tid >> 6;
  const int wr = w >> 2;   // 0..1: rows [wr*64, +64)
  const int wc = w & 3;    // 0..3: cols [wc*64, +64)
  const int lrow = lane & 15;
  const int g = lane >> 4;
  const int kphys = ((g ^ ((lrow >> 1) & 3)) << 4);  // physical 16B chunk byte

  // XCD-aware bijective swizzle (grid = 2048, divisible by 8).
  int id = blockIdx.x;
  id = (id & 7) * (gridDim.x >> 3) + (id >> 3);
  const int bm = (id >> 4) << 7;  // 128 m-tiles
  const int bn = (id & 15) << 8;  // 16 n-tiles

  const char* lAs = (const char*)As;
  const char* lBs = (const char*)Bs;

  // ---- wave-uniform mask bits in SGPRs -----------------------------------
  // Compute bits: wave col-group wc covers B rows [wc*64,+64) -> mask rows
  // (bn>>5)+wc*2 and +1.
  const unsigned* cp = maskbits + (((bn >> 5) + wc * 2) << 2);
  const u64 m0lo = (u64)__builtin_amdgcn_readfirstlane(cp[0]) |
                   ((u64)__builtin_amdgcn_readfirstlane(cp[1]) << 32);
  const u64 m0hi = (u64)__builtin_amdgcn_readfirstlane(cp[2]) |
                   ((u64)__builtin_amdgcn_readfirstlane(cp[3]) << 32);
  const u64 m1lo = (u64)__builtin_amdgcn_readfirstlane(cp[4]) |
                   ((u64)__builtin_amdgcn_readfirstlane(cp[5]) << 32);
  const u64 m1hi = (u64)__builtin_amdgcn_readfirstlane(cp[6]) |
                   ((u64)__builtin_amdgcn_readfirstlane(cp[7]) << 32);
  // Staging bits: wave w stages B rows [w*16,+16) (op0, mask row (w>>1)) and
  // +128 (op1, mask row 4+(w>>1)).
  const unsigned* sp0 = maskbits + (((bn >> 5) + (w >> 1)) << 2);
  const unsigned* sp1 = maskbits + (((bn >> 5) + 4 + (w >> 1)) << 2);
  const u64 sg0lo = (u64)__builtin_amdgcn_readfirstlane(sp0[0]) |
                    ((u64)__builtin_amdgcn_readfirstlane(sp0[1]) << 32);
  const u64 sg0hi = (u64)__builtin_amdgcn_readfirstlane(sp0[2]) |
                    ((u64)__builtin_amdgcn_readfirstlane(sp0[3]) << 32);
  const u64 sg1lo = (u64)__builtin_amdgcn_readfirstlane(sp1[0]) |
                    ((u64)__builtin_amdgcn_readfirstlane(sp1[1]) << 32);
  const u64 sg1hi = (u64)__builtin_amdgcn_readfirstlane(sp1[2]) |
                    ((u64)__builtin_amdgcn_readfirstlane(sp1[3]) << 32);

  // Staging geometry: thread -> row tid>>2, 16B chunk tid&3.
  const int sr = tid >> 2;
  const int sc8 = (tid & 3) * 8;
  const u16* gaBase = xb + (size_t)(bm + sr) * K_TOT + sc8;       // A rows 0..127
  const u16* gb0Base = wb + (size_t)(bn + sr) * K_TOT + sc8;      // B rows 0..127
  const u16* gb1Base = gb0Base + (size_t)128 * K_TOT;             // B rows 128..255

  f32x4 acc[4][4] = {};

  auto stage = [&](int t) {
    const int s = t & 1;
    const int k0 = t << 5;
    const int sh = t & 63;
    const u64 s0 = (t & 64) ? sg0hi : sg0lo;
    const u64 s1 = (t & 64) ? sg1hi : sg1lo;
    const u16* ga = gaBase + k0;
    // Redirect skipped B loads to the A source (L1-hit dummy): op count and
    // LDS-dest layout stay fixed, so counted vmcnt remains valid.
    const u16* gb0 = ((int)((s0 >> sh) & 1)) ? gb0Base + k0 : ga;
    const u16* gb1 = ((int)((s1 >> sh) & 1)) ? gb1Base + k0 : ga;
    u16* la = As + s * 4096 + w * 512;             // wave-uniform dest base
    u16* lb = Bs + s * 8192 + w * 512;
    load16_to_lds(ga, la);
    load16_to_lds(gb0, lb);
    load16_to_lds(gb1, lb + 4096);
  };

  // Prologue: stage tile 0 (3 ops in flight).
  stage(0);

#define TILE(t, VMSTR)                                                        \
  {                                                                           \
    const int s_ = (t) & 1;                                                   \
    const int abase = s_ * 8192;                                              \
    const int bbase = s_ * 16384;                                             \
    __builtin_amdgcn_s_barrier();  /* slot (t+1)&1 readers (tile t-1) done */ \
    if ((t) + 1 < NT) stage((t) + 1);                                         \
    asm volatile("s_waitcnt " VMSTR ::: "memory"); /* stage(t) landed */      \
    __builtin_amdgcn_s_barrier();  /* all waves' stage(t) landed */           \
    const int sh = (t) & 63;                                                  \
    const u64 sel0 = ((t) & 64) ? m0hi : m0lo;                                \
    const u64 sel1 = ((t) & 64) ? m1hi : m1lo;                                \
    const int b0 = (int)((sel0 >> sh) & 1);                                   \
    const int b1 = (int)((sel1 >> sh) & 1);                                   \
    if (b0 | b1) {                                                            \
      s16x8 af[4];                                                            \
      _Pragma("unroll") for (int m = 0; m < 4; ++m)                           \
          af[m] = *(const s16x8*)(lAs + abase +                               \
                                  (wr * 64 + m * 16 + lrow) * 64 + kphys);    \
      s16x8 bfv[4];                                                           \
      if (b0) {                                                               \
        bfv[0] = *(const s16x8*)(lBs + bbase +                                \
                                 (wc * 64 + 0 * 16 + lrow) * 64 + kphys);     \
        bfv[1] = *(const s16x8*)(lBs + bbase +                                \
                                 (wc * 64 + 1 * 16 + lrow) * 64 + kphys);     \
      }                                                                       \
      if (b1) {                                                               \
        bfv[2] = *(const s16x8*)(lBs + bbase +                                \
                                 (wc * 64 + 2 * 16 + lrow) * 64 + kphys);     \
        bfv[3] = *(const s16x8*)(lBs + bbase +                                \
                                 (wc * 64 + 3 * 16 + lrow) * 64 + kphys);     \
      }                                                                       \
      asm volatile("s_waitcnt lgkmcnt(0)" ::: "memory");                      \
      __builtin_amdgcn_sched_barrier(0);                                      \
      __builtin_amdgcn_s_setprio(1);                                          \
      if (b0) {                                                               \
        _Pragma("unroll") for (int m = 0; m < 4; ++m) {                       \
          acc[m][0] = __builtin_amdgcn_mfma_f32_16x16x32_bf16(                \
              af[m], bfv[0], acc[m][0], 0, 0, 0);                             \
          acc[m][1] = __builtin_amdgcn_mfma_f32_16x16x32_bf16(                \
              af[m], bfv[1], acc[m][1], 0, 0, 0);                             \
        }                                                                     \
      }                                                                       \
      if (b1) {                                                               \
        _Pragma("unroll") for (int m = 0; m < 4; ++m) {                       \
          acc[m][2] = __builtin_amdgcn_mfma_f32_16x16x32_bf16(                \
              af[m], bfv[2], acc[m][2], 0, 0, 0);                             \
          acc[m][3] = __builtin_amdgcn_mfma_f32_16x16x32_bf16(                \
              af[m], bfv[3], acc[m][3], 0, 0, 0);                             \
        }                                                                     \
      }                                                                       \
      __builtin_amdgcn_s_setprio(0);                                          \
    }                                                                         \
  }

  for (int t = 0; t < NT - 1; ++t) TILE(t, "vmcnt(3)");
  TILE(NT - 1, "vmcnt(0)");
#undef TILE

  // Epilogue: out = 2*acc + bias. C/D frag: col = lane&15, row = g*4 + j.
#pragma unroll
  for (int n = 0; n < 4; ++n) {
    const int gcol = bn + wc * 64 + n * 16 + lrow;
    const float bv = bias[gcol];
#pragma unroll
    for (int m = 0; m < 4; ++m) {
      const int grow = bm + wr * 64 + m * 16 + (g << 2);
#pragma unroll
      for (int j = 0; j < 4; ++j)
        out[(size_t)(grow + j) * N_TOT + gcol] = 2.0f * acc[m][n][j] + bv;
    }
  }
}

// ---------------------------------------------------------------------------
// Legacy reg-staged GEMM (fallback when ws can't hold xb).
// ---------------------------------------------------------------------------
template <bool PREPPED>
__global__ __launch_bounds__(256) void gemm_kernel(
    const float* __restrict__ x, const u16* __restrict__ wb,
    const float* __restrict__ wf, const unsigned char* __restrict__ mask8,
    const float* __restrict__ bias, float* __restrict__ out) {
  __shared__ __align__(16) u16 Asl[128 * LDS_STRIDE];
  __shared__ __align__(16) u16 Bsl[128 * LDS_STRIDE];

  const int tid = threadIdx.x;
  const int lane = tid & 63;
  const int wave = tid >> 6;
  const int wr = wave >> 1;
  const int wcn = wave & 1;

  int id = blockIdx.x;
  const int cpx = gridDim.x >> 3;
  id = (id & 7) * cpx + (id >> 3);
  const int bm = (id >> 5) << 7;
  const int bn = (id & 31) << 7;

  const int arow = tid >> 4;
  const int acol = (tid & 15) << 2;
  const int brow = tid >> 3;
  const int bcol = (tid & 7) << 3;

  const int lrow = lane & 15;
  const int lgo = (lane >> 4) << 3;

  f32x4 acc[4][4] = {};

  for (int k0 = 0; k0 < K_TOT; k0 += 64) {
#pragma unroll
    for (int r = 0; r < 8; ++r) {
      const int row = arow + r * 16;
      const float4 v = *reinterpret_cast<const float4*>(
          x + (size_t)(bm + row) * K_TOT + k0 + acol);
      ushort4 bvec;
      bvec.x = f2bf(v.x); bvec.y = f2bf(v.y); bvec.z = f2bf(v.z); bvec.w = f2bf(v.w);
      *reinterpret_cast<ushort4*>(&Asl[row * LDS_STRIDE + acol]) = bvec;
    }
    if (PREPPED) {
#pragma unroll
      for (int r = 0; r < 4; ++r) {
        const int row = brow + r * 32;
        const s16x8 v = *reinterpret_cast<const s16x8*>(
            wb + (size_t)(bn + row) * K_TOT + k0 + bcol);
        *reinterpret_cast<s16x8*>(&Bsl[row * LDS_STRIDE + bcol]) = v;
      }
    } else {
#pragma unroll
      for (int r = 0; r < 8; ++r) {
        const int row = arow + r * 16;
        const float4 v = *reinterpret_cast<const float4*>(
            wf + (size_t)(bm + row) * K_TOT + k0 + acol);
        ushort4 bvec;
        bvec.x = 0; bvec.y = 0; bvec.z = 0; bvec.w = 0;
        if (mask8[((bn + row) >> 5) * MASK_DIM + ((k0 + acol) >> 5)]) {
          bvec.x = f2bf(v.x); bvec.y = f2bf(v.y); bvec.z = f2bf(v.z); bvec.w = f2bf(v.w);
        }
        *reinterpret_cast<ushort4*>(&Bsl[row * LDS_STRIDE + acol]) = bvec;
      }
    }
    __syncthreads();

#pragma unroll
    for (int ks = 0; ks < 2; ++ks) {
      s16x8 af[4], bfv[4];
#pragma unroll
      for (int m = 0; m < 4; ++m)
        af[m] = *reinterpret_cast<const s16x8*>(
            &Asl[(wr * 64 + m * 16 + lrow) * LDS_STRIDE + ks * 32 + lgo]);
#pragma unroll
      for (int n = 0; n < 4; ++n)
        bfv[n] = *reinterpret_cast<const s16x8*>(
            &Bsl[(wcn * 64 + n * 16 + lrow) * LDS_STRIDE + ks * 32 + lgo]);
#pragma unroll
      for (int m = 0; m < 4; ++m)
#pragma unroll
        for (int n = 0; n < 4; ++n)
          acc[m][n] = __builtin_amdgcn_mfma_f32_16x16x32_bf16(af[m], bfv[n],
                                                              acc[m][n], 0, 0, 0);
    }
    __syncthreads();
  }

#pragma unroll
  for (int n = 0; n < 4; ++n) {
    const int gcol = bn + wcn * 64 + n * 16 + lrow;
    const float bv = bias[gcol];
#pragma unroll
    for (int m = 0; m < 4; ++m) {
      const int grow = bm + wr * 64 + m * 16 + ((lane >> 4) << 2);
#pragma unroll
      for (int j = 0; j < 4; ++j) {
        out[(size_t)(grow + j) * N_TOT + gcol] = 2.0f * acc[m][n][j] + bv;
      }
    }
  }
}

extern "C" void kernel_launch(void* const* d_in, const int* in_sizes, int n_in,
                              void* d_out, int out_size, void* d_ws, size_t ws_size,
                              hipStream_t stream) {
  const float* x = (const float*)d_in[0];
  const float* w = (const float*)d_in[1];
  const float* bias = (const float*)d_in[2];
  const unsigned char* mask_raw = (const unsigned char*)d_in[3];
  float* out = (float*)d_out;

  unsigned char* ws_mask = (unsigned char*)d_ws;            // 16 KiB mask8
  unsigned* ws_bits = (unsigned*)((char*)d_ws + 16384);     // 2 KiB bitmask
  u16* wb = (u16*)((char*)d_ws + 65536);                    // 32 MiB bf16 W
  u16* xb = (u16*)((char*)d_ws + 65536 +
                   (size_t)N_TOT * K_TOT * sizeof(u16));    // 128 MiB bf16 x
  const size_t need_w = 65536 + (size_t)N_TOT * K_TOT * sizeof(u16);
  const size_t need_full = need_w + (size_t)M_TOT * K_TOT * sizeof(u16);

  prep_mask_kernel<<<1, 256, 0, stream>>>(mask_raw, ws_mask, ws_bits);

  if (ws_size >= need_full) {
    prep_w_swz_kernel<<<(N_TOT * (K_TOT / 8)) / 256, 256, 0, stream>>>(w, ws_mask, wb);
    prep_x_swz_kernel<<<(M_TOT * (K_TOT / 8)) / 256, 256, 0, stream>>>(x, xb);
    gemm_v8_kernel<<<(M_TOT / 128) * (N_TOT / 256), 512, 0, stream>>>(
        xb, wb, ws_bits, bias, out);
  } else if (ws_size >= need_w) {
    prep_w_kernel<<<(N_TOT * K_TOT) / (256 * 4), 256, 0, stream>>>(w, ws_mask, wb);
    gemm_kernel<true><<<(M_TOT / 128) * (N_TOT / 128), 256, 0, stream>>>(
        x, wb, nullptr, nullptr, bias, out);
  } else {
    gemm_kernel<false><<<(M_TOT / 128) * (N_TOT / 128), 256, 0, stream>>>(
        x, nullptr, w, ws_mask, bias, out);
  }
}

// Round 10
// 571.906 us; speedup vs baseline: 6.6401x; 1.1754x over previous
//
#include <hip/hip_runtime.h>

// BlockSparseLinear: out[M,N] = 2 * (x[M,K] @ (W .* mask)^T) + bias[N]
// M = 16384, N = 4096, K = 4096, mask 32x32 blocks over (128,128).
// v10 = v9 with the double-swizzle bug fixed: prep stores xb/wb PRE-SWIZZLED
// (16B chunk c -> c ^ (row&7) within each 128B span), so the GEMM staging
// source must be LINEAR (schk*8) -- v9 wrongly XORed the source again,
// canceling the prep swizzle while the read side still applied the XOR.
// Everything else identical: m201-style 8-phase schedule, 256x256 tile,
// BK=64, 8 waves (2Mx4N), acc[8][4], 128 KiB LDS (2 slots x {A 32K, B 32K}),
// counted vmcnt(4) at p0/p4 only, per-phase {ds_read || 1 half-tile stage ->
// barrier -> lgkmcnt(0) -> setprio(1) -> 16 MFMA}, SGPR-bitmask sparsity
// gating (bfv reads, af ks-halves, B-stage redirect, MFMA sub-clusters).

typedef short s16x8 __attribute__((ext_vector_type(8)));
typedef float f32x4 __attribute__((ext_vector_type(4)));
typedef unsigned short u16;
typedef unsigned long long u64;

#define M_TOT 16384
#define N_TOT 4096
#define K_TOT 4096
#define MASK_DIM 128
#define LDS_STRIDE 72  // legacy fallback kernel only

__device__ __forceinline__ u16 f2bf(float f) {
  union { float f; unsigned u; } v; v.f = f;
  unsigned r = v.u + 0x7FFFu + ((v.u >> 16) & 1u);  // round-to-nearest-even
  return (u16)(r >> 16);
}

__device__ __forceinline__ void load16_to_lds(const u16* g, u16* l) {
  __builtin_amdgcn_global_load_lds(
      (const __attribute__((address_space(1))) void*)g,
      (__attribute__((address_space(3))) void*)l, 16, 0, 0);
}

// ---------------------------------------------------------------------------
// Mask normalization (format auto-detect) + bit-pack (maskbits[row][4] u32).
// ---------------------------------------------------------------------------
__global__ void prep_mask_kernel(const unsigned char* __restrict__ m,
                                 unsigned char* __restrict__ outm,
                                 unsigned* __restrict__ outbits) {
  __shared__ int s_ok[4];
  const int t = threadIdx.x;
  unsigned v = reinterpret_cast<const unsigned*>(m)[t];
  bool wordlike = (v <= 1u) || (v == 0x3F800000u);
  unsigned long long b = __ballot(wordlike);
  if ((t & 63) == 0) s_ok[t >> 6] = (b == ~0ull) ? 1 : 0;
  __syncthreads();
  const bool word_fmt = s_ok[0] && s_ok[1] && s_ok[2] && s_ok[3];
  for (int i = t; i < MASK_DIM * MASK_DIM; i += 256) {
    bool nz = word_fmt ? (reinterpret_cast<const unsigned*>(m)[i] != 0u)
                       : (m[i] != 0);
    outm[i] = nz ? 1 : 0;
  }
  __syncthreads();
  for (int i = t; i < MASK_DIM * 4; i += 256) {
    const int r = i >> 2, w = i & 3;
    unsigned acc = 0;
    for (int bit = 0; bit < 32; ++bit)
      acc |= (unsigned)(outm[r * MASK_DIM + w * 32 + bit] != 0) << bit;
    outbits[i] = acc;
  }
}

// ---------------------------------------------------------------------------
// x fp32 [M][K] -> bf16, pre-swizzled: within each 64-elem span (128B), 16B
// chunk c goes to slot c ^ (row&7).
// ---------------------------------------------------------------------------
__global__ void prep_x_swz_kernel(const float* __restrict__ x,
                                  u16* __restrict__ xb) {
  const size_t t = (size_t)blockIdx.x * 256 + threadIdx.x;  // 16B-chunk index
  const size_t row = t >> 9;        // 512 chunks per 4096-elem row
  const int wc = (int)(t & 511);
  const int blk = wc >> 3;          // 128B span 0..63
  const int c = wc & 7;             // chunk within span
  const float4 v0 = *reinterpret_cast<const float4*>(x + row * K_TOT + wc * 8);
  const float4 v1 = *reinterpret_cast<const float4*>(x + row * K_TOT + wc * 8 + 4);
  s16x8 b;
  b[0] = (short)f2bf(v0.x); b[1] = (short)f2bf(v0.y);
  b[2] = (short)f2bf(v0.z); b[3] = (short)f2bf(v0.w);
  b[4] = (short)f2bf(v1.x); b[5] = (short)f2bf(v1.y);
  b[6] = (short)f2bf(v1.z); b[7] = (short)f2bf(v1.w);
  *reinterpret_cast<s16x8*>(xb + row * K_TOT + blk * 64 +
                            (size_t)((c ^ ((int)row & 7)) * 8)) = b;
}

// ---------------------------------------------------------------------------
// W fp32 [N][K] -> masked bf16, pre-swizzled (same scheme).
// ---------------------------------------------------------------------------
__global__ void prep_w_swz_kernel(const float* __restrict__ w,
                                  const unsigned char* __restrict__ mask8,
                                  u16* __restrict__ wb) {
  const size_t t = (size_t)blockIdx.x * 256 + threadIdx.x;
  const size_t row = t >> 9;
  const int wc = (int)(t & 511);
  const int blk = wc >> 3;
  const int c = wc & 7;
  s16x8 b = {};
  if (mask8[((int)row >> 5) * MASK_DIM + (wc >> 2)]) {
    const float4 v0 = *reinterpret_cast<const float4*>(w + row * K_TOT + wc * 8);
    const float4 v1 = *reinterpret_cast<const float4*>(w + row * K_TOT + wc * 8 + 4);
    b[0] = (short)f2bf(v0.x); b[1] = (short)f2bf(v0.y);
    b[2] = (short)f2bf(v0.z); b[3] = (short)f2bf(v0.w);
    b[4] = (short)f2bf(v1.x); b[5] = (short)f2bf(v1.y);
    b[6] = (short)f2bf(v1.z); b[7] = (short)f2bf(v1.w);
  }
  *reinterpret_cast<s16x8*>(wb + row * K_TOT + blk * 64 +
                            (size_t)((c ^ ((int)row & 7)) * 8)) = b;
}

// ---------------------------------------------------------------------------
// Legacy linear prep_w (for the ws-fits-W-only fallback path).
// ---------------------------------------------------------------------------
__global__ void prep_w_kernel(const float* __restrict__ w,
                              const unsigned char* __restrict__ mask8,
                              u16* __restrict__ wb) {
  const size_t e = ((size_t)blockIdx.x * blockDim.x + threadIdx.x) * 4;
  const int n = (int)(e >> 12);
  const int k = (int)(e & 4095);
  const float4 v = *reinterpret_cast<const float4*>(w + e);
  ushort4 bvec;
  if (mask8[(n >> 5) * MASK_DIM + (k >> 5)]) {
    bvec.x = f2bf(v.x); bvec.y = f2bf(v.y); bvec.z = f2bf(v.z); bvec.w = f2bf(v.w);
  } else {
    bvec.x = 0; bvec.y = 0; bvec.z = 0; bvec.w = 0;
  }
  *reinterpret_cast<ushort4*>(wb + e) = bvec;
}

// ---------------------------------------------------------------------------
// v10 GEMM: 8-phase schedule.  C = 2 * A @ B^T + bias.
// ---------------------------------------------------------------------------
#define BITS2(LO, HI, t) \
  ((int)(((((t) & 32) ? (HI) : (LO)) >> (((t) & 31) * 2)) & 3))

#define MF(A, B, C) __builtin_amdgcn_mfma_f32_16x16x32_bf16(A, B, C, 0, 0, 0)

__global__ __launch_bounds__(512, 2) void gemm_8p_kernel(
    const u16* __restrict__ xb, const u16* __restrict__ wb,
    const unsigned* __restrict__ maskbits,
    const float* __restrict__ bias, float* __restrict__ out) {
  extern __shared__ __align__(16) u16 lds[];  // A[2][256][64] | B[2][256][64]

  const int tid = threadIdx.x;
  const int lane = tid & 63;
  const int w = tid >> 6;
  const int wr = w >> 2;   // 0..1: output rows [wr*128, +128)
  const int wc = w & 3;    // 0..3: output cols [wc*64, +64)
  const int lrow = lane & 15;
  const int g = lane >> 4;
  const int sw = (lrow & 7) << 4;  // read-side XOR

  // XCD-aware bijective swizzle (grid = 1024, divisible by 8).
  int id = blockIdx.x;
  id = (id & 7) * (gridDim.x >> 3) + (id >> 3);
  const int bm = (id >> 4) << 8;  // 64 m-tiles
  const int bn = (id & 15) << 8;  // 16 n-tiles

  const char* ldsb = (const char*)lds;

  // ---- wave-uniform mask bits in SGPRs -----------------------------------
  // Compute bits: wave col-group wc -> mask rows (bn>>5)+wc*2, +1.
  const unsigned* cp = maskbits + (((bn >> 5) + wc * 2) << 2);
  const u64 m0lo = (u64)__builtin_amdgcn_readfirstlane(cp[0]) |
                   ((u64)__builtin_amdgcn_readfirstlane(cp[1]) << 32);
  const u64 m0hi = (u64)__builtin_amdgcn_readfirstlane(cp[2]) |
                   ((u64)__builtin_amdgcn_readfirstlane(cp[3]) << 32);
  const u64 m1lo = (u64)__builtin_amdgcn_readfirstlane(cp[4]) |
                   ((u64)__builtin_amdgcn_readfirstlane(cp[5]) << 32);
  const u64 m1hi = (u64)__builtin_amdgcn_readfirstlane(cp[6]) |
                   ((u64)__builtin_amdgcn_readfirstlane(cp[7]) << 32);
  // Staging bits: B half h, op o covers W rows bn + h*128+o*64 + w*8..+7
  // -> mask row (bn>>5) + (w>>2) + 4h + 2o.
  const int sbase = (bn >> 5) + (w >> 2);
  const unsigned* q0 = maskbits + ((sbase + 0) << 2);
  const unsigned* q1 = maskbits + ((sbase + 2) << 2);
  const unsigned* q2 = maskbits + ((sbase + 4) << 2);
  const unsigned* q3 = maskbits + ((sbase + 6) << 2);
  const u64 sb0lo = (u64)__builtin_amdgcn_readfirstlane(q0[0]) |
                    ((u64)__builtin_amdgcn_readfirstlane(q0[1]) << 32);
  const u64 sb0hi = (u64)__builtin_amdgcn_readfirstlane(q0[2]) |
                    ((u64)__builtin_amdgcn_readfirstlane(q0[3]) << 32);
  const u64 sb1lo = (u64)__builtin_amdgcn_readfirstlane(q1[0]) |
                    ((u64)__builtin_amdgcn_readfirstlane(q1[1]) << 32);
  const u64 sb1hi = (u64)__builtin_amdgcn_readfirstlane(q1[2]) |
                    ((u64)__builtin_amdgcn_readfirstlane(q1[3]) << 32);
  const u64 sb2lo = (u64)__builtin_amdgcn_readfirstlane(q2[0]) |
                    ((u64)__builtin_amdgcn_readfirstlane(q2[1]) << 32);
  const u64 sb2hi = (u64)__builtin_amdgcn_readfirstlane(q2[2]) |
                    ((u64)__builtin_amdgcn_readfirstlane(q2[3]) << 32);
  const u64 sb3lo = (u64)__builtin_amdgcn_readfirstlane(q3[0]) |
                    ((u64)__builtin_amdgcn_readfirstlane(q3[1]) << 32);
  const u64 sb3hi = (u64)__builtin_amdgcn_readfirstlane(q3[2]) |
                    ((u64)__builtin_amdgcn_readfirstlane(q3[3]) << 32);

  // Staging geometry: thread -> row tid>>3 (0..63), 16B chunk tid&7.
  // SOURCE IS LINEAR: prep already stored the swizzle (v9 bug was XORing
  // here a second time, which canceled it).
  const int srow = tid >> 3;
  const int schk = tid & 7;
  const u16* aSrc = xb + (size_t)(bm + srow) * K_TOT + (size_t)(schk << 3);
  const u16* bSrc = wb + (size_t)(bn + srow) * K_TOT + (size_t)(schk << 3);

  f32x4 acc[8][4] = {};

  // ---- staging macros -----------------------------------------------------
#define STAGE_A(t, h, slot)                                                   \
  _Pragma("unroll") for (int o = 0; o < 2; ++o)                               \
      load16_to_lds(aSrc + (size_t)((h)*128 + o * 64) * K_TOT + (t)*64,       \
                    (u16*)((char*)lds + (slot)*32768 + (h)*16384 + o * 8192 + \
                           w * 1024));

#define STAGE_B(t, h, slot, L0, H0, L1, H1)                                   \
  {                                                                           \
    const int k0_ = BITS2(L0, H0, t);                                         \
    const int k1_ = BITS2(L1, H1, t);                                         \
    load16_to_lds(k0_ ? bSrc + (size_t)((h)*128) * K_TOT + (t)*64             \
                      : aSrc + (t)*64,                                        \
                  (u16*)((char*)lds + 65536 + (slot)*32768 + (h)*16384 +      \
                         w * 1024));                                          \
    load16_to_lds(k1_ ? bSrc + (size_t)((h)*128 + 64) * K_TOT + (t)*64        \
                      : aSrc + (size_t)64 * K_TOT + (t)*64,                   \
                  (u16*)((char*)lds + 65536 + (slot)*32768 + (h)*16384 +      \
                         8192 + w * 1024));                                   \
  }

#define AF_READS(slot, q, ANY)                                                \
  _Pragma("unroll") for (int ks = 0; ks < 2; ++ks) {                          \
    if (((ANY) >> ks) & 1) {                                                  \
      _Pragma("unroll") for (int m = 0; m < 2; ++m)                           \
          af[m][ks] = *(const s16x8*)(ldsb + (slot)*32768 +                   \
                                      (wr * 128 + (q)*32 + m * 16 + lrow) *   \
                                          128 +                              \
                                      ((ks * 64 + g * 16) ^ sw));             \
    }                                                                         \
  }

#define BF_READS(slot, G0, G1)                                                \
  _Pragma("unroll") for (int ks = 0; ks < 2; ++ks) {                          \
    if (((G0) >> ks) & 1) {                                                   \
      bfv[0][ks] = *(const s16x8*)(ldsb + 65536 + (slot)*32768 +              \
                                   (wc * 64 + 0 + lrow) * 128 +               \
                                   ((ks * 64 + g * 16) ^ sw));                \
      bfv[1][ks] = *(const s16x8*)(ldsb + 65536 + (slot)*32768 +              \
                                   (wc * 64 + 16 + lrow) * 128 +              \
                                   ((ks * 64 + g * 16) ^ sw));                \
    }                                                                         \
    if (((G1) >> ks) & 1) {                                                   \
      bfv[2][ks] = *(const s16x8*)(ldsb + 65536 + (slot)*32768 +              \
                                   (wc * 64 + 32 + lrow) * 128 +              \
                                   ((ks * 64 + g * 16) ^ sw));                \
      bfv[3][ks] = *(const s16x8*)(ldsb + 65536 + (slot)*32768 +              \
                                   (wc * 64 + 48 + lrow) * 128 +              \
                                   ((ks * 64 + g * 16) ^ sw));                \
    }                                                                         \
  }

#define MFMA_CL(q, G0, G1)                                                    \
  asm volatile("s_waitcnt lgkmcnt(0)" ::: "memory");                          \
  __builtin_amdgcn_sched_barrier(0);                                          \
  __builtin_amdgcn_s_setprio(1);                                              \
  _Pragma("unroll") for (int ks = 0; ks < 2; ++ks) {                          \
    if (((G0) >> ks) & 1) {                                                   \
      _Pragma("unroll") for (int m = 0; m < 2; ++m) {                         \
        acc[(q)*2 + m][0] = MF(af[m][ks], bfv[0][ks], acc[(q)*2 + m][0]);     \
        acc[(q)*2 + m][1] = MF(af[m][ks], bfv[1][ks], acc[(q)*2 + m][1]);     \
      }                                                                       \
    }                                                                         \
    if (((G1) >> ks) & 1) {                                                   \
      _Pragma("unroll") for (int m = 0; m < 2; ++m) {                         \
        acc[(q)*2 + m][2] = MF(af[m][ks], bfv[2][ks], acc[(q)*2 + m][2]);     \
        acc[(q)*2 + m][3] = MF(af[m][ks], bfv[3][ks], acc[(q)*2 + m][3]);     \
      }                                                                       \
    }                                                                         \
  }                                                                           \
  __builtin_amdgcn_s_setprio(0);

  // Prologue: T0 fully (8 loads), then T1.B (4 loads) -> 12 in flight.
  STAGE_B(0, 0, 0, sb0lo, sb0hi, sb1lo, sb1hi);
  STAGE_B(0, 1, 0, sb2lo, sb2hi, sb3lo, sb3hi);
  STAGE_A(0, 0, 0);
  STAGE_A(0, 1, 0);
  STAGE_B(1, 0, 1, sb0lo, sb0hi, sb1lo, sb1hi);
  STAGE_B(1, 1, 1, sb2lo, sb2hi, sb3lo, sb3hi);

  for (int i = 0; i < 32; ++i) {
    const int t0 = 2 * i, t1 = 2 * i + 1;
    const int u0 = (t0 + 2 < 64) ? t0 + 2 : 63;  // clamped tail keeps vmcnt
    const int u1 = (t1 + 2 < 64) ? t1 + 2 : 63;  // counts + is hazard-safe
    const int ga0 = BITS2(m0lo, m0hi, t0), ga1 = BITS2(m1lo, m1hi, t0);
    const int gb0 = BITS2(m0lo, m0hi, t1), gb1 = BITS2(m1lo, m1hi, t1);
    const int anyA = ga0 | ga1, anyB = gb0 | gb1;
    s16x8 af[2][2];
    s16x8 bfv[4][2];

    // ---- p0 (tile t0, slot0) ----
    asm volatile("s_waitcnt vmcnt(4)" ::: "memory");
    __builtin_amdgcn_s_barrier();
    BF_READS(0, ga0, ga1);
    AF_READS(0, 0, anyA);
    STAGE_A(t1, 0, 1);
    MFMA_CL(0, ga0, ga1);
    // ---- p1 ----
    AF_READS(0, 1, anyA);
    STAGE_A(t1, 1, 1);
    __builtin_amdgcn_s_barrier();
    MFMA_CL(1, ga0, ga1);
    // ---- p2 ----
    AF_READS(0, 2, anyA);
    STAGE_B(u0, 0, 0, sb0lo, sb0hi, sb1lo, sb1hi);
    __builtin_amdgcn_s_barrier();
    MFMA_CL(2, ga0, ga1);
    // ---- p3 ----
    AF_READS(0, 3, anyA);
    STAGE_B(u0, 1, 0, sb2lo, sb2hi, sb3lo, sb3hi);
    __builtin_amdgcn_s_barrier();
    MFMA_CL(3, ga0, ga1);
    // ---- p4 (tile t1, slot1) ----
    asm volatile("s_waitcnt vmcnt(4)" ::: "memory");
    __builtin_amdgcn_s_barrier();
    BF_READS(1, gb0, gb1);
    AF_READS(1, 0, anyB);
    STAGE_A(u0, 0, 0);
    MFMA_CL(0, gb0, gb1);
    // ---- p5 ----
    AF_READS(1, 1, anyB);
    STAGE_A(u0, 1, 0);
    __builtin_amdgcn_s_barrier();
    MFMA_CL(1, gb0, gb1);
    // ---- p6 ----
    AF_READS(1, 2, anyB);
    STAGE_B(u1, 0, 1, sb0lo, sb0hi, sb1lo, sb1hi);
    __builtin_amdgcn_s_barrier();
    MFMA_CL(2, gb0, gb1);
    // ---- p7 ----
    AF_READS(1, 3, anyB);
    STAGE_B(u1, 1, 1, sb2lo, sb2hi, sb3lo, sb3hi);
    __builtin_amdgcn_s_barrier();
    MFMA_CL(3, gb0, gb1);
  }

#undef STAGE_A
#undef STAGE_B
#undef AF_READS
#undef BF_READS
#undef MFMA_CL

  // Epilogue: out = 2*acc + bias. C/D frag: col = lane&15, row = g*4 + j.
#pragma unroll
  for (int n = 0; n < 4; ++n) {
    const int gcol = bn + wc * 64 + n * 16 + lrow;
    const float bv = bias[gcol];
#pragma unroll
    for (int m = 0; m < 8; ++m) {
      const int grow = bm + wr * 128 + m * 16 + (g << 2);
#pragma unroll
      for (int j = 0; j < 4; ++j)
        out[(size_t)(grow + j) * N_TOT + gcol] = 2.0f * acc[m][n][j] + bv;
    }
  }
}

// ---------------------------------------------------------------------------
// Legacy reg-staged GEMM (fallback when ws can't hold xb).
// ---------------------------------------------------------------------------
template <bool PREPPED>
__global__ __launch_bounds__(256) void gemm_kernel(
    const float* __restrict__ x, const u16* __restrict__ wb,
    const float* __restrict__ wf, const unsigned char* __restrict__ mask8,
    const float* __restrict__ bias, float* __restrict__ out) {
  __shared__ __align__(16) u16 Asl[128 * LDS_STRIDE];
  __shared__ __align__(16) u16 Bsl[128 * LDS_STRIDE];

  const int tid = threadIdx.x;
  const int lane = tid & 63;
  const int wave = tid >> 6;
  const int wr = wave >> 1;
  const int wcn = wave & 1;

  int id = blockIdx.x;
  const int cpx = gridDim.x >> 3;
  id = (id & 7) * cpx + (id >> 3);
  const int bm = (id >> 5) << 7;
  const int bn = (id & 31) << 7;

  const int arow = tid >> 4;
  const int acol = (tid & 15) << 2;
  const int brow = tid >> 3;
  const int bcol = (tid & 7) << 3;

  const int lrow = lane & 15;
  const int lgo = (lane >> 4) << 3;

  f32x4 acc[4][4] = {};

  for (int k0 = 0; k0 < K_TOT; k0 += 64) {
#pragma unroll
    for (int r = 0; r < 8; ++r) {
      const int row = arow + r * 16;
      const float4 v = *reinterpret_cast<const float4*>(
          x + (size_t)(bm + row) * K_TOT + k0 + acol);
      ushort4 bvec;
      bvec.x = f2bf(v.x); bvec.y = f2bf(v.y); bvec.z = f2bf(v.z); bvec.w = f2bf(v.w);
      *reinterpret_cast<ushort4*>(&Asl[row * LDS_STRIDE + acol]) = bvec;
    }
    if (PREPPED) {
#pragma unroll
      for (int r = 0; r < 4; ++r) {
        const int row = brow + r * 32;
        const s16x8 v = *reinterpret_cast<const s16x8*>(
            wb + (size_t)(bn + row) * K_TOT + k0 + bcol);
        *reinterpret_cast<s16x8*>(&Bsl[row * LDS_STRIDE + bcol]) = v;
      }
    } else {
#pragma unroll
      for (int r = 0; r < 8; ++r) {
        const int row = arow + r * 16;
        const float4 v = *reinterpret_cast<const float4*>(
            wf + (size_t)(bn + row) * K_TOT + k0 + acol);
        ushort4 bvec;
        bvec.x = 0; bvec.y = 0; bvec.z = 0; bvec.w = 0;
        if (mask8[((bn + row) >> 5) * MASK_DIM + ((k0 + acol) >> 5)]) {
          bvec.x = f2bf(v.x); bvec.y = f2bf(v.y); bvec.z = f2bf(v.z); bvec.w = f2bf(v.w);
        }
        *reinterpret_cast<ushort4*>(&Bsl[row * LDS_STRIDE + acol]) = bvec;
      }
    }
    __syncthreads();

#pragma unroll
    for (int ks = 0; ks < 2; ++ks) {
      s16x8 af[4], bfv[4];
#pragma unroll
      for (int m = 0; m < 4; ++m)
        af[m] = *reinterpret_cast<const s16x8*>(
            &Asl[(wr * 64 + m * 16 + lrow) * LDS_STRIDE + ks * 32 + lgo]);
#pragma unroll
      for (int n = 0; n < 4; ++n)
        bfv[n] = *reinterpret_cast<const s16x8*>(
            &Bsl[(wcn * 64 + n * 16 + lrow) * LDS_STRIDE + ks * 32 + lgo]);
#pragma unroll
      for (int m = 0; m < 4; ++m)
#pragma unroll
        for (int n = 0; n < 4; ++n)
          acc[m][n] = __builtin_amdgcn_mfma_f32_16x16x32_bf16(af[m], bfv[n],
                                                              acc[m][n], 0, 0, 0);
    }
    __syncthreads();
  }

#pragma unroll
  for (int n = 0; n < 4; ++n) {
    const int gcol = bn + wcn * 64 + n * 16 + lrow;
    const float bv = bias[gcol];
#pragma unroll
    for (int m = 0; m < 4; ++m) {
      const int grow = bm + wr * 64 + m * 16 + ((lane >> 4) << 2);
#pragma unroll
      for (int j = 0; j < 4; ++j) {
        out[(size_t)(grow + j) * N_TOT + gcol] = 2.0f * acc[m][n][j] + bv;
      }
    }
  }
}

extern "C" void kernel_launch(void* const* d_in, const int* in_sizes, int n_in,
                              void* d_out, int out_size, void* d_ws, size_t ws_size,
                              hipStream_t stream) {
  const float* x = (const float*)d_in[0];
  const float* w = (const float*)d_in[1];
  const float* bias = (const float*)d_in[2];
  const unsigned char* mask_raw = (const unsigned char*)d_in[3];
  float* out = (float*)d_out;

  unsigned char* ws_mask = (unsigned char*)d_ws;            // 16 KiB mask8
  unsigned* ws_bits = (unsigned*)((char*)d_ws + 16384);     // 2 KiB bitmask
  u16* wb = (u16*)((char*)d_ws + 65536);                    // 32 MiB bf16 W
  u16* xb = (u16*)((char*)d_ws + 65536 +
                   (size_t)N_TOT * K_TOT * sizeof(u16));    // 128 MiB bf16 x
  const size_t need_w = 65536 + (size_t)N_TOT * K_TOT * sizeof(u16);
  const size_t need_full = need_w + (size_t)M_TOT * K_TOT * sizeof(u16);

  prep_mask_kernel<<<1, 256, 0, stream>>>(mask_raw, ws_mask, ws_bits);

  if (ws_size >= need_full) {
    prep_w_swz_kernel<<<(N_TOT * (K_TOT / 8)) / 256, 256, 0, stream>>>(w, ws_mask, wb);
    prep_x_swz_kernel<<<(M_TOT * (K_TOT / 8)) / 256, 256, 0, stream>>>(x, xb);
    hipFuncSetAttribute(reinterpret_cast<const void*>(gemm_8p_kernel),
                        hipFuncAttributeMaxDynamicSharedMemorySize, 131072);
    gemm_8p_kernel<<<(M_TOT / 256) * (N_TOT / 256), 512, 131072, stream>>>(
        xb, wb, ws_bits, bias, out);
  } else if (ws_size >= need_w) {
    prep_w_kernel<<<(N_TOT * K_TOT) / (256 * 4), 256, 0, stream>>>(w, ws_mask, wb);
    gemm_kernel<true><<<(M_TOT / 128) * (N_TOT / 128), 256, 0, stream>>>(
        x, wb, nullptr, nullptr, bias, out);
  } else {
    gemm_kernel<false><<<(M_TOT / 128) * (N_TOT / 128), 256, 0, stream>>>(
        x, nullptr, w, ws_mask, bias, out);
  }
}

// Round 11
// 544.665 us; speedup vs baseline: 6.9722x; 1.0500x over previous
//
#include <hip/hip_runtime.h>

// BlockSparseLinear: out[M,N] = 2 * (x[M,K] @ (W .* mask)^T) + bias[N]
// M = 16384, N = 4096, K = 4096, mask 32x32 blocks over (128,128).
// v11: DENSE m201-style 8-phase GEMM over prepped operands. Round-10 proved
// wave-uniform sparsity gating gives zero wall-time benefit (tile duration =
// max over waves at every barrier; MfmaUtil 31% == 62% x 0.5 density) while
// its branches poison the static schedule. wb's zero blocks make the dense
// accumulate numerically identical to the gated version.
// Structure: 256x256 tile, BK=64, 8 waves (2Mx4N), acc[8][4], 128 KiB LDS
// (2 slots x {A 32K, B 32K}), counted vmcnt(4) at p0/p4 only (never 0 in the
// loop; clamped-tail dummy stages keep the count invariant), per phase:
// {4 af ds_read (+8 bfv at tile start) || stage 1 half-tile (2 gload_lds) ->
// barrier -> lgkmcnt(0) -> sched_barrier -> setprio(1) -> 16 MFMA}.
// Operands pre-swizzled in d_ws (chunk c -> c ^ (row&7) per 128B span);
// staging source LINEAR (double-swizzle bug fixed in v10).

typedef short s16x8 __attribute__((ext_vector_type(8)));
typedef float f32x4 __attribute__((ext_vector_type(4)));
typedef unsigned short u16;
typedef unsigned long long u64;

#define M_TOT 16384
#define N_TOT 4096
#define K_TOT 4096
#define MASK_DIM 128
#define LDS_STRIDE 72  // legacy fallback kernel only

__device__ __forceinline__ u16 f2bf(float f) {
  union { float f; unsigned u; } v; v.f = f;
  unsigned r = v.u + 0x7FFFu + ((v.u >> 16) & 1u);  // round-to-nearest-even
  return (u16)(r >> 16);
}

__device__ __forceinline__ void load16_to_lds(const u16* g, u16* l) {
  __builtin_amdgcn_global_load_lds(
      (const __attribute__((address_space(1))) void*)g,
      (__attribute__((address_space(3))) void*)l, 16, 0, 0);
}

// ---------------------------------------------------------------------------
// Mask normalization (format auto-detect: byte-bool vs int32/float words).
// ---------------------------------------------------------------------------
__global__ void prep_mask_kernel(const unsigned char* __restrict__ m,
                                 unsigned char* __restrict__ outm) {
  __shared__ int s_ok[4];
  const int t = threadIdx.x;
  unsigned v = reinterpret_cast<const unsigned*>(m)[t];
  bool wordlike = (v <= 1u) || (v == 0x3F800000u);
  unsigned long long b = __ballot(wordlike);
  if ((t & 63) == 0) s_ok[t >> 6] = (b == ~0ull) ? 1 : 0;
  __syncthreads();
  const bool word_fmt = s_ok[0] && s_ok[1] && s_ok[2] && s_ok[3];
  for (int i = t; i < MASK_DIM * MASK_DIM; i += 256) {
    bool nz = word_fmt ? (reinterpret_cast<const unsigned*>(m)[i] != 0u)
                       : (m[i] != 0);
    outm[i] = nz ? 1 : 0;
  }
}

// ---------------------------------------------------------------------------
// x fp32 [M][K] -> bf16, pre-swizzled: within each 64-elem span (128B), 16B
// chunk c goes to slot c ^ (row&7).
// ---------------------------------------------------------------------------
__global__ void prep_x_swz_kernel(const float* __restrict__ x,
                                  u16* __restrict__ xb) {
  const size_t t = (size_t)blockIdx.x * 256 + threadIdx.x;  // 16B-chunk index
  const size_t row = t >> 9;        // 512 chunks per 4096-elem row
  const int wc = (int)(t & 511);
  const int blk = wc >> 3;          // 128B span 0..63
  const int c = wc & 7;             // chunk within span
  const float4 v0 = *reinterpret_cast<const float4*>(x + row * K_TOT + wc * 8);
  const float4 v1 = *reinterpret_cast<const float4*>(x + row * K_TOT + wc * 8 + 4);
  s16x8 b;
  b[0] = (short)f2bf(v0.x); b[1] = (short)f2bf(v0.y);
  b[2] = (short)f2bf(v0.z); b[3] = (short)f2bf(v0.w);
  b[4] = (short)f2bf(v1.x); b[5] = (short)f2bf(v1.y);
  b[6] = (short)f2bf(v1.z); b[7] = (short)f2bf(v1.w);
  *reinterpret_cast<s16x8*>(xb + row * K_TOT + blk * 64 +
                            (size_t)((c ^ ((int)row & 7)) * 8)) = b;
}

// ---------------------------------------------------------------------------
// W fp32 [N][K] -> masked bf16, pre-swizzled (same scheme).
// ---------------------------------------------------------------------------
__global__ void prep_w_swz_kernel(const float* __restrict__ w,
                                  const unsigned char* __restrict__ mask8,
                                  u16* __restrict__ wb) {
  const size_t t = (size_t)blockIdx.x * 256 + threadIdx.x;
  const size_t row = t >> 9;
  const int wc = (int)(t & 511);
  const int blk = wc >> 3;
  const int c = wc & 7;
  s16x8 b = {};
  if (mask8[((int)row >> 5) * MASK_DIM + (wc >> 2)]) {
    const float4 v0 = *reinterpret_cast<const float4*>(w + row * K_TOT + wc * 8);
    const float4 v1 = *reinterpret_cast<const float4*>(w + row * K_TOT + wc * 8 + 4);
    b[0] = (short)f2bf(v0.x); b[1] = (short)f2bf(v0.y);
    b[2] = (short)f2bf(v0.z); b[3] = (short)f2bf(v0.w);
    b[4] = (short)f2bf(v1.x); b[5] = (short)f2bf(v1.y);
    b[6] = (short)f2bf(v1.z); b[7] = (short)f2bf(v1.w);
  }
  *reinterpret_cast<s16x8*>(wb + row * K_TOT + blk * 64 +
                            (size_t)((c ^ ((int)row & 7)) * 8)) = b;
}

// ---------------------------------------------------------------------------
// Legacy linear prep_w (for the ws-fits-W-only fallback path).
// ---------------------------------------------------------------------------
__global__ void prep_w_kernel(const float* __restrict__ w,
                              const unsigned char* __restrict__ mask8,
                              u16* __restrict__ wb) {
  const size_t e = ((size_t)blockIdx.x * blockDim.x + threadIdx.x) * 4;
  const int n = (int)(e >> 12);
  const int k = (int)(e & 4095);
  const float4 v = *reinterpret_cast<const float4*>(w + e);
  ushort4 bvec;
  if (mask8[(n >> 5) * MASK_DIM + (k >> 5)]) {
    bvec.x = f2bf(v.x); bvec.y = f2bf(v.y); bvec.z = f2bf(v.z); bvec.w = f2bf(v.w);
  } else {
    bvec.x = 0; bvec.y = 0; bvec.z = 0; bvec.w = 0;
  }
  *reinterpret_cast<ushort4*>(wb + e) = bvec;
}

// ---------------------------------------------------------------------------
// v11 GEMM: dense 8-phase schedule.  C = 2 * A @ B^T + bias.
// ---------------------------------------------------------------------------
#define MF(A, B, C) __builtin_amdgcn_mfma_f32_16x16x32_bf16(A, B, C, 0, 0, 0)

__global__ __launch_bounds__(512, 2) void gemm_8p_kernel(
    const u16* __restrict__ xb, const u16* __restrict__ wb,
    const float* __restrict__ bias, float* __restrict__ out) {
  extern __shared__ __align__(16) u16 lds[];  // A[2][256][64] | B[2][256][64]

  const int tid = threadIdx.x;
  const int lane = tid & 63;
  const int w = tid >> 6;
  const int wr = w >> 2;   // 0..1: output rows [wr*128, +128)
  const int wc = w & 3;    // 0..3: output cols [wc*64, +64)
  const int lrow = lane & 15;
  const int g = lane >> 4;
  const int sw = (lrow & 7) << 4;  // read-side XOR

  // XCD-aware bijective swizzle (grid = 1024, divisible by 8).
  int id = blockIdx.x;
  id = (id & 7) * (gridDim.x >> 3) + (id >> 3);
  const int bm = (id >> 4) << 8;  // 64 m-tiles
  const int bn = (id & 15) << 8;  // 16 n-tiles

  const char* ldsb = (const char*)lds;

  // Staging geometry: thread -> row tid>>3 (0..63), 16B chunk tid&7.
  // Source is LINEAR: prep already stored the swizzle.
  const int srow = tid >> 3;
  const int schk = tid & 7;
  const u16* aSrc = xb + (size_t)(bm + srow) * K_TOT + (size_t)(schk << 3);
  const u16* bSrc = wb + (size_t)(bn + srow) * K_TOT + (size_t)(schk << 3);

  f32x4 acc[8][4] = {};

  // ---- staging macros -----------------------------------------------------
#define STAGE_A(t, h, slot)                                                   \
  _Pragma("unroll") for (int o = 0; o < 2; ++o)                               \
      load16_to_lds(aSrc + (size_t)((h)*128 + o * 64) * K_TOT + (t)*64,       \
                    (u16*)((char*)lds + (slot)*32768 + (h)*16384 + o * 8192 + \
                           w * 1024));

#define STAGE_B(t, h, slot)                                                   \
  _Pragma("unroll") for (int o = 0; o < 2; ++o)                               \
      load16_to_lds(bSrc + (size_t)((h)*128 + o * 64) * K_TOT + (t)*64,       \
                    (u16*)((char*)lds + 65536 + (slot)*32768 + (h)*16384 +    \
                           o * 8192 + w * 1024));

#define AF_READS(slot, q)                                                     \
  _Pragma("unroll") for (int ks = 0; ks < 2; ++ks)                            \
      _Pragma("unroll") for (int m = 0; m < 2; ++m)                           \
          af[m][ks] = *(const s16x8*)(ldsb + (slot)*32768 +                   \
                                      (wr * 128 + (q)*32 + m * 16 + lrow) *   \
                                          128 +                              \
                                      ((ks * 64 + g * 16) ^ sw));

#define BF_READS(slot)                                                        \
  _Pragma("unroll") for (int ks = 0; ks < 2; ++ks)                            \
      _Pragma("unroll") for (int n = 0; n < 4; ++n)                           \
          bfv[n][ks] = *(const s16x8*)(ldsb + 65536 + (slot)*32768 +          \
                                       (wc * 64 + n * 16 + lrow) * 128 +      \
                                       ((ks * 64 + g * 16) ^ sw));

#define MFMA_CL(q)                                                            \
  asm volatile("s_waitcnt lgkmcnt(0)" ::: "memory");                          \
  __builtin_amdgcn_sched_barrier(0);                                          \
  __builtin_amdgcn_s_setprio(1);                                              \
  _Pragma("unroll") for (int ks = 0; ks < 2; ++ks)                            \
      _Pragma("unroll") for (int m = 0; m < 2; ++m)                           \
          _Pragma("unroll") for (int n = 0; n < 4; ++n)                       \
              acc[(q)*2 + m][n] =                                             \
                  MF(af[m][ks], bfv[n][ks], acc[(q)*2 + m][n]);               \
  __builtin_amdgcn_s_setprio(0);

  // Prologue: T0 full (8 loads), then T1.B (4 loads) -> 12 in flight.
  STAGE_B(0, 0, 0);
  STAGE_B(0, 1, 0);
  STAGE_A(0, 0, 0);
  STAGE_A(0, 1, 0);
  STAGE_B(1, 0, 1);
  STAGE_B(1, 1, 1);

  for (int i = 0; i < 32; ++i) {
    const int t0 = 2 * i, t1 = 2 * i + 1;
    const int u0 = (t0 + 2 < 64) ? t0 + 2 : 63;  // clamped tail keeps vmcnt
    const int u1 = (t1 + 2 < 64) ? t1 + 2 : 63;  // counts + is hazard-safe
    s16x8 af[2][2];
    s16x8 bfv[4][2];

    // ---- p0 (tile t0, slot0) ----
    asm volatile("s_waitcnt vmcnt(4)" ::: "memory");
    __builtin_amdgcn_s_barrier();
    BF_READS(0);
    AF_READS(0, 0);
    STAGE_A(t1, 0, 1);
    MFMA_CL(0);
    // ---- p1 ----
    AF_READS(0, 1);
    STAGE_A(t1, 1, 1);
    __builtin_amdgcn_s_barrier();
    MFMA_CL(1);
    // ---- p2 ----
    AF_READS(0, 2);
    STAGE_B(u0, 0, 0);
    __builtin_amdgcn_s_barrier();
    MFMA_CL(2);
    // ---- p3 ----
    AF_READS(0, 3);
    STAGE_B(u0, 1, 0);
    __builtin_amdgcn_s_barrier();
    MFMA_CL(3);
    // ---- p4 (tile t1, slot1) ----
    asm volatile("s_waitcnt vmcnt(4)" ::: "memory");
    __builtin_amdgcn_s_barrier();
    BF_READS(1);
    AF_READS(1, 0);
    STAGE_A(u0, 0, 0);
    MFMA_CL(0);
    // ---- p5 ----
    AF_READS(1, 1);
    STAGE_A(u0, 1, 0);
    __builtin_amdgcn_s_barrier();
    MFMA_CL(1);
    // ---- p6 ----
    AF_READS(1, 2);
    STAGE_B(u1, 0, 1);
    __builtin_amdgcn_s_barrier();
    MFMA_CL(2);
    // ---- p7 ----
    AF_READS(1, 3);
    STAGE_B(u1, 1, 1);
    __builtin_amdgcn_s_barrier();
    MFMA_CL(3);
  }

#undef STAGE_A
#undef STAGE_B
#undef AF_READS
#undef BF_READS
#undef MFMA_CL

  // Epilogue: out = 2*acc + bias. C/D frag: col = lane&15, row = g*4 + j.
#pragma unroll
  for (int n = 0; n < 4; ++n) {
    const int gcol = bn + wc * 64 + n * 16 + lrow;
    const float bv = bias[gcol];
#pragma unroll
    for (int m = 0; m < 8; ++m) {
      const int grow = bm + wr * 128 + m * 16 + (g << 2);
#pragma unroll
      for (int j = 0; j < 4; ++j)
        out[(size_t)(grow + j) * N_TOT + gcol] = 2.0f * acc[m][n][j] + bv;
    }
  }
}

// ---------------------------------------------------------------------------
// Legacy reg-staged GEMM (fallback when ws can't hold xb).
// ---------------------------------------------------------------------------
template <bool PREPPED>
__global__ __launch_bounds__(256) void gemm_kernel(
    const float* __restrict__ x, const u16* __restrict__ wb,
    const float* __restrict__ wf, const unsigned char* __restrict__ mask8,
    const float* __restrict__ bias, float* __restrict__ out) {
  __shared__ __align__(16) u16 Asl[128 * LDS_STRIDE];
  __shared__ __align__(16) u16 Bsl[128 * LDS_STRIDE];

  const int tid = threadIdx.x;
  const int lane = tid & 63;
  const int wave = tid >> 6;
  const int wr = wave >> 1;
  const int wcn = wave & 1;

  int id = blockIdx.x;
  const int cpx = gridDim.x >> 3;
  id = (id & 7) * cpx + (id >> 3);
  const int bm = (id >> 5) << 7;
  const int bn = (id & 31) << 7;

  const int arow = tid >> 4;
  const int acol = (tid & 15) << 2;
  const int brow = tid >> 3;
  const int bcol = (tid & 7) << 3;

  const int lrow = lane & 15;
  const int lgo = (lane >> 4) << 3;

  f32x4 acc[4][4] = {};

  for (int k0 = 0; k0 < K_TOT; k0 += 64) {
#pragma unroll
    for (int r = 0; r < 8; ++r) {
      const int row = arow + r * 16;
      const float4 v = *reinterpret_cast<const float4*>(
          x + (size_t)(bm + row) * K_TOT + k0 + acol);
      ushort4 bvec;
      bvec.x = f2bf(v.x); bvec.y = f2bf(v.y); bvec.z = f2bf(v.z); bvec.w = f2bf(v.w);
      *reinterpret_cast<ushort4*>(&Asl[row * LDS_STRIDE + acol]) = bvec;
    }
    if (PREPPED) {
#pragma unroll
      for (int r = 0; r < 4; ++r) {
        const int row = brow + r * 32;
        const s16x8 v = *reinterpret_cast<const s16x8*>(
            wb + (size_t)(bn + row) * K_TOT + k0 + bcol);
        *reinterpret_cast<s16x8*>(&Bsl[row * LDS_STRIDE + bcol]) = v;
      }
    } else {
#pragma unroll
      for (int r = 0; r < 8; ++r) {
        const int row = arow + r * 16;
        const float4 v = *reinterpret_cast<const float4*>(
            wf + (size_t)(bn + row) * K_TOT + k0 + acol);
        ushort4 bvec;
        bvec.x = 0; bvec.y = 0; bvec.z = 0; bvec.w = 0;
        if (mask8[((bn + row) >> 5) * MASK_DIM + ((k0 + acol) >> 5)]) {
          bvec.x = f2bf(v.x); bvec.y = f2bf(v.y); bvec.z = f2bf(v.z); bvec.w = f2bf(v.w);
        }
        *reinterpret_cast<ushort4*>(&Bsl[row * LDS_STRIDE + acol]) = bvec;
      }
    }
    __syncthreads();

#pragma unroll
    for (int ks = 0; ks < 2; ++ks) {
      s16x8 af[4], bfv[4];
#pragma unroll
      for (int m = 0; m < 4; ++m)
        af[m] = *reinterpret_cast<const s16x8*>(
            &Asl[(wr * 64 + m * 16 + lrow) * LDS_STRIDE + ks * 32 + lgo]);
#pragma unroll
      for (int n = 0; n < 4; ++n)
        bfv[n] = *reinterpret_cast<const s16x8*>(
            &Bsl[(wcn * 64 + n * 16 + lrow) * LDS_STRIDE + ks * 32 + lgo]);
#pragma unroll
      for (int m = 0; m < 4; ++m)
#pragma unroll
        for (int n = 0; n < 4; ++n)
          acc[m][n] = __builtin_amdgcn_mfma_f32_16x16x32_bf16(af[m], bfv[n],
                                                              acc[m][n], 0, 0, 0);
    }
    __syncthreads();
  }

#pragma unroll
  for (int n = 0; n < 4; ++n) {
    const int gcol = bn + wcn * 64 + n * 16 + lrow;
    const float bv = bias[gcol];
#pragma unroll
    for (int m = 0; m < 4; ++m) {
      const int grow = bm + wr * 64 + m * 16 + ((lane >> 4) << 2);
#pragma unroll
      for (int j = 0; j < 4; ++j) {
        out[(size_t)(grow + j) * N_TOT + gcol] = 2.0f * acc[m][n][j] + bv;
      }
    }
  }
}

extern "C" void kernel_launch(void* const* d_in, const int* in_sizes, int n_in,
                              void* d_out, int out_size, void* d_ws, size_t ws_size,
                              hipStream_t stream) {
  const float* x = (const float*)d_in[0];
  const float* w = (const float*)d_in[1];
  const float* bias = (const float*)d_in[2];
  const unsigned char* mask_raw = (const unsigned char*)d_in[3];
  float* out = (float*)d_out;

  unsigned char* ws_mask = (unsigned char*)d_ws;            // 16 KiB mask8
  u16* wb = (u16*)((char*)d_ws + 65536);                    // 32 MiB bf16 W
  u16* xb = (u16*)((char*)d_ws + 65536 +
                   (size_t)N_TOT * K_TOT * sizeof(u16));    // 128 MiB bf16 x
  const size_t need_w = 65536 + (size_t)N_TOT * K_TOT * sizeof(u16);
  const size_t need_full = need_w + (size_t)M_TOT * K_TOT * sizeof(u16);

  prep_mask_kernel<<<1, 256, 0, stream>>>(mask_raw, ws_mask);

  if (ws_size >= need_full) {
    prep_w_swz_kernel<<<(N_TOT * (K_TOT / 8)) / 256, 256, 0, stream>>>(w, ws_mask, wb);
    prep_x_swz_kernel<<<(M_TOT * (K_TOT / 8)) / 256, 256, 0, stream>>>(x, xb);
    hipFuncSetAttribute(reinterpret_cast<const void*>(gemm_8p_kernel),
                        hipFuncAttributeMaxDynamicSharedMemorySize, 131072);
    gemm_8p_kernel<<<(M_TOT / 256) * (N_TOT / 256), 512, 131072, stream>>>(
        xb, wb, bias, out);
  } else if (ws_size >= need_w) {
    prep_w_kernel<<<(N_TOT * K_TOT) / (256 * 4), 256, 0, stream>>>(w, ws_mask, wb);
    gemm_kernel<true><<<(M_TOT / 128) * (N_TOT / 128), 256, 0, stream>>>(
        x, wb, nullptr, nullptr, bias, out);
  } else {
    gemm_kernel<false><<<(M_TOT / 128) * (N_TOT / 128), 256, 0, stream>>>(
        x, nullptr, w, ws_mask, bias, out);
  }
}

// Round 12
// 529.266 us; speedup vs baseline: 7.1750x; 1.0291x over previous
//
#include <hip/hip_runtime.h>

// BlockSparseLinear: out[M,N] = 2 * (x[M,K] @ (W .* mask)^T) + bias[N]
// M = 16384, N = 4096, K = 4096, mask 32x32 blocks over (128,128).
// v12 = v11 (dense m201-style 8-phase GEMM, 256x256 tile, BK=64, 8 waves,
// acc[8][4], 128 KiB LDS 2-slot, counted vmcnt(4) at p0/p4, per-phase
// {ds_read || half-tile stage -> barrier -> lgkmcnt(0) -> setprio MFMA}) with
// ONE delta: L2-panel-resident block mapping. Workgroup i lands on XCD i%8;
// we map XCD x -> bn in {2x, 2x+1} only (bm sweeps 0..63), so each XCD's
// B working set = 2 panels x 2 MiB = 4 MiB = its L2. v11's mapping cycled
// all 16 B panels through each XCD's L2 (36 MiB working set -> L3/HBM
// thrash, FETCH 620 MB vs ~160 compulsory).

typedef short s16x8 __attribute__((ext_vector_type(8)));
typedef float f32x4 __attribute__((ext_vector_type(4)));
typedef unsigned short u16;
typedef unsigned long long u64;

#define M_TOT 16384
#define N_TOT 4096
#define K_TOT 4096
#define MASK_DIM 128
#define LDS_STRIDE 72  // legacy fallback kernel only

__device__ __forceinline__ u16 f2bf(float f) {
  union { float f; unsigned u; } v; v.f = f;
  unsigned r = v.u + 0x7FFFu + ((v.u >> 16) & 1u);  // round-to-nearest-even
  return (u16)(r >> 16);
}

__device__ __forceinline__ void load16_to_lds(const u16* g, u16* l) {
  __builtin_amdgcn_global_load_lds(
      (const __attribute__((address_space(1))) void*)g,
      (__attribute__((address_space(3))) void*)l, 16, 0, 0);
}

// ---------------------------------------------------------------------------
// Mask normalization (format auto-detect: byte-bool vs int32/float words).
// ---------------------------------------------------------------------------
__global__ void prep_mask_kernel(const unsigned char* __restrict__ m,
                                 unsigned char* __restrict__ outm) {
  __shared__ int s_ok[4];
  const int t = threadIdx.x;
  unsigned v = reinterpret_cast<const unsigned*>(m)[t];
  bool wordlike = (v <= 1u) || (v == 0x3F800000u);
  unsigned long long b = __ballot(wordlike);
  if ((t & 63) == 0) s_ok[t >> 6] = (b == ~0ull) ? 1 : 0;
  __syncthreads();
  const bool word_fmt = s_ok[0] && s_ok[1] && s_ok[2] && s_ok[3];
  for (int i = t; i < MASK_DIM * MASK_DIM; i += 256) {
    bool nz = word_fmt ? (reinterpret_cast<const unsigned*>(m)[i] != 0u)
                       : (m[i] != 0);
    outm[i] = nz ? 1 : 0;
  }
}

// ---------------------------------------------------------------------------
// x fp32 [M][K] -> bf16, pre-swizzled: within each 64-elem span (128B), 16B
// chunk c goes to slot c ^ (row&7).
// ---------------------------------------------------------------------------
__global__ void prep_x_swz_kernel(const float* __restrict__ x,
                                  u16* __restrict__ xb) {
  const size_t t = (size_t)blockIdx.x * 256 + threadIdx.x;  // 16B-chunk index
  const size_t row = t >> 9;        // 512 chunks per 4096-elem row
  const int wc = (int)(t & 511);
  const int blk = wc >> 3;          // 128B span 0..63
  const int c = wc & 7;             // chunk within span
  const float4 v0 = *reinterpret_cast<const float4*>(x + row * K_TOT + wc * 8);
  const float4 v1 = *reinterpret_cast<const float4*>(x + row * K_TOT + wc * 8 + 4);
  s16x8 b;
  b[0] = (short)f2bf(v0.x); b[1] = (short)f2bf(v0.y);
  b[2] = (short)f2bf(v0.z); b[3] = (short)f2bf(v0.w);
  b[4] = (short)f2bf(v1.x); b[5] = (short)f2bf(v1.y);
  b[6] = (short)f2bf(v1.z); b[7] = (short)f2bf(v1.w);
  *reinterpret_cast<s16x8*>(xb + row * K_TOT + blk * 64 +
                            (size_t)((c ^ ((int)row & 7)) * 8)) = b;
}

// ---------------------------------------------------------------------------
// W fp32 [N][K] -> masked bf16, pre-swizzled (same scheme).
// ---------------------------------------------------------------------------
__global__ void prep_w_swz_kernel(const float* __restrict__ w,
                                  const unsigned char* __restrict__ mask8,
                                  u16* __restrict__ wb) {
  const size_t t = (size_t)blockIdx.x * 256 + threadIdx.x;
  const size_t row = t >> 9;
  const int wc = (int)(t & 511);
  const int blk = wc >> 3;
  const int c = wc & 7;
  s16x8 b = {};
  if (mask8[((int)row >> 5) * MASK_DIM + (wc >> 2)]) {
    const float4 v0 = *reinterpret_cast<const float4*>(w + row * K_TOT + wc * 8);
    const float4 v1 = *reinterpret_cast<const float4*>(w + row * K_TOT + wc * 8 + 4);
    b[0] = (short)f2bf(v0.x); b[1] = (short)f2bf(v0.y);
    b[2] = (short)f2bf(v0.z); b[3] = (short)f2bf(v0.w);
    b[4] = (short)f2bf(v1.x); b[5] = (short)f2bf(v1.y);
    b[6] = (short)f2bf(v1.z); b[7] = (short)f2bf(v1.w);
  }
  *reinterpret_cast<s16x8*>(wb + row * K_TOT + blk * 64 +
                            (size_t)((c ^ ((int)row & 7)) * 8)) = b;
}

// ---------------------------------------------------------------------------
// Legacy linear prep_w (for the ws-fits-W-only fallback path).
// ---------------------------------------------------------------------------
__global__ void prep_w_kernel(const float* __restrict__ w,
                              const unsigned char* __restrict__ mask8,
                              u16* __restrict__ wb) {
  const size_t e = ((size_t)blockIdx.x * blockDim.x + threadIdx.x) * 4;
  const int n = (int)(e >> 12);
  const int k = (int)(e & 4095);
  const float4 v = *reinterpret_cast<const float4*>(w + e);
  ushort4 bvec;
  if (mask8[(n >> 5) * MASK_DIM + (k >> 5)]) {
    bvec.x = f2bf(v.x); bvec.y = f2bf(v.y); bvec.z = f2bf(v.z); bvec.w = f2bf(v.w);
  } else {
    bvec.x = 0; bvec.y = 0; bvec.z = 0; bvec.w = 0;
  }
  *reinterpret_cast<ushort4*>(wb + e) = bvec;
}

// ---------------------------------------------------------------------------
// v12 GEMM: dense 8-phase schedule, L2-panel-resident block mapping.
// C = 2 * A @ B^T + bias.
// ---------------------------------------------------------------------------
#define MF(A, B, C) __builtin_amdgcn_mfma_f32_16x16x32_bf16(A, B, C, 0, 0, 0)

__global__ __launch_bounds__(512, 2) void gemm_8p_kernel(
    const u16* __restrict__ xb, const u16* __restrict__ wb,
    const float* __restrict__ bias, float* __restrict__ out) {
  extern __shared__ __align__(16) u16 lds[];  // A[2][256][64] | B[2][256][64]

  const int tid = threadIdx.x;
  const int lane = tid & 63;
  const int w = tid >> 6;
  const int wr = w >> 2;   // 0..1: output rows [wr*128, +128)
  const int wc = w & 3;    // 0..3: output cols [wc*64, +64)
  const int lrow = lane & 15;
  const int g = lane >> 4;
  const int sw = (lrow & 7) << 4;  // read-side XOR

  // L2-panel-resident mapping: workgroup i runs on XCD i%8. XCD x owns
  // bn in {2x, 2x+1} (2 B-panels = 4 MiB = its L2); bm sweeps 0..63.
  const int xcd = blockIdx.x & 7;
  const int jj = blockIdx.x >> 3;         // 0..127 within the XCD
  const int bn = ((xcd << 1) | (jj & 1)) << 8;
  const int bm = (jj >> 1) << 8;

  const char* ldsb = (const char*)lds;

  // Staging geometry: thread -> row tid>>3 (0..63), 16B chunk tid&7.
  // Source is LINEAR: prep already stored the swizzle.
  const int srow = tid >> 3;
  const int schk = tid & 7;
  const u16* aSrc = xb + (size_t)(bm + srow) * K_TOT + (size_t)(schk << 3);
  const u16* bSrc = wb + (size_t)(bn + srow) * K_TOT + (size_t)(schk << 3);

  f32x4 acc[8][4] = {};

  // ---- staging macros -----------------------------------------------------
#define STAGE_A(t, h, slot)                                                   \
  _Pragma("unroll") for (int o = 0; o < 2; ++o)                               \
      load16_to_lds(aSrc + (size_t)((h)*128 + o * 64) * K_TOT + (t)*64,       \
                    (u16*)((char*)lds + (slot)*32768 + (h)*16384 + o * 8192 + \
                           w * 1024));

#define STAGE_B(t, h, slot)                                                   \
  _Pragma("unroll") for (int o = 0; o < 2; ++o)                               \
      load16_to_lds(bSrc + (size_t)((h)*128 + o * 64) * K_TOT + (t)*64,       \
                    (u16*)((char*)lds + 65536 + (slot)*32768 + (h)*16384 +    \
                           o * 8192 + w * 1024));

#define AF_READS(slot, q)                                                     \
  _Pragma("unroll") for (int ks = 0; ks < 2; ++ks)                            \
      _Pragma("unroll") for (int m = 0; m < 2; ++m)                           \
          af[m][ks] = *(const s16x8*)(ldsb + (slot)*32768 +                   \
                                      (wr * 128 + (q)*32 + m * 16 + lrow) *   \
                                          128 +                              \
                                      ((ks * 64 + g * 16) ^ sw));

#define BF_READS(slot)                                                        \
  _Pragma("unroll") for (int ks = 0; ks < 2; ++ks)                            \
      _Pragma("unroll") for (int n = 0; n < 4; ++n)                           \
          bfv[n][ks] = *(const s16x8*)(ldsb + 65536 + (slot)*32768 +          \
                                       (wc * 64 + n * 16 + lrow) * 128 +      \
                                       ((ks * 64 + g * 16) ^ sw));

#define MFMA_CL(q)                                                            \
  asm volatile("s_waitcnt lgkmcnt(0)" ::: "memory");                          \
  __builtin_amdgcn_sched_barrier(0);                                          \
  __builtin_amdgcn_s_setprio(1);                                              \
  _Pragma("unroll") for (int ks = 0; ks < 2; ++ks)                            \
      _Pragma("unroll") for (int m = 0; m < 2; ++m)                           \
          _Pragma("unroll") for (int n = 0; n < 4; ++n)                       \
              acc[(q)*2 + m][n] =                                             \
                  MF(af[m][ks], bfv[n][ks], acc[(q)*2 + m][n]);               \
  __builtin_amdgcn_s_setprio(0);

  // Prologue: T0 full (8 loads), then T1.B (4 loads) -> 12 in flight.
  STAGE_B(0, 0, 0);
  STAGE_B(0, 1, 0);
  STAGE_A(0, 0, 0);
  STAGE_A(0, 1, 0);
  STAGE_B(1, 0, 1);
  STAGE_B(1, 1, 1);

  for (int i = 0; i < 32; ++i) {
    const int t0 = 2 * i, t1 = 2 * i + 1;
    const int u0 = (t0 + 2 < 64) ? t0 + 2 : 63;  // clamped tail keeps vmcnt
    const int u1 = (t1 + 2 < 64) ? t1 + 2 : 63;  // counts + is hazard-safe
    s16x8 af[2][2];
    s16x8 bfv[4][2];

    // ---- p0 (tile t0, slot0) ----
    asm volatile("s_waitcnt vmcnt(4)" ::: "memory");
    __builtin_amdgcn_s_barrier();
    BF_READS(0);
    AF_READS(0, 0);
    STAGE_A(t1, 0, 1);
    MFMA_CL(0);
    // ---- p1 ----
    AF_READS(0, 1);
    STAGE_A(t1, 1, 1);
    __builtin_amdgcn_s_barrier();
    MFMA_CL(1);
    // ---- p2 ----
    AF_READS(0, 2);
    STAGE_B(u0, 0, 0);
    __builtin_amdgcn_s_barrier();
    MFMA_CL(2);
    // ---- p3 ----
    AF_READS(0, 3);
    STAGE_B(u0, 1, 0);
    __builtin_amdgcn_s_barrier();
    MFMA_CL(3);
    // ---- p4 (tile t1, slot1) ----
    asm volatile("s_waitcnt vmcnt(4)" ::: "memory");
    __builtin_amdgcn_s_barrier();
    BF_READS(1);
    AF_READS(1, 0);
    STAGE_A(u0, 0, 0);
    MFMA_CL(0);
    // ---- p5 ----
    AF_READS(1, 1);
    STAGE_A(u0, 1, 0);
    __builtin_amdgcn_s_barrier();
    MFMA_CL(1);
    // ---- p6 ----
    AF_READS(1, 2);
    STAGE_B(u1, 0, 1);
    __builtin_amdgcn_s_barrier();
    MFMA_CL(2);
    // ---- p7 ----
    AF_READS(1, 3);
    STAGE_B(u1, 1, 1);
    __builtin_amdgcn_s_barrier();
    MFMA_CL(3);
  }

#undef STAGE_A
#undef STAGE_B
#undef AF_READS
#undef BF_READS
#undef MFMA_CL

  // Epilogue: out = 2*acc + bias. C/D frag: col = lane&15, row = g*4 + j.
#pragma unroll
  for (int n = 0; n < 4; ++n) {
    const int gcol = bn + wc * 64 + n * 16 + lrow;
    const float bv = bias[gcol];
#pragma unroll
    for (int m = 0; m < 8; ++m) {
      const int grow = bm + wr * 128 + m * 16 + (g << 2);
#pragma unroll
      for (int j = 0; j < 4; ++j)
        out[(size_t)(grow + j) * N_TOT + gcol] = 2.0f * acc[m][n][j] + bv;
    }
  }
}

// ---------------------------------------------------------------------------
// Legacy reg-staged GEMM (fallback when ws can't hold xb).
// ---------------------------------------------------------------------------
template <bool PREPPED>
__global__ __launch_bounds__(256) void gemm_kernel(
    const float* __restrict__ x, const u16* __restrict__ wb,
    const float* __restrict__ wf, const unsigned char* __restrict__ mask8,
    const float* __restrict__ bias, float* __restrict__ out) {
  __shared__ __align__(16) u16 Asl[128 * LDS_STRIDE];
  __shared__ __align__(16) u16 Bsl[128 * LDS_STRIDE];

  const int tid = threadIdx.x;
  const int lane = tid & 63;
  const int wave = tid >> 6;
  const int wr = wave >> 1;
  const int wcn = wave & 1;

  int id = blockIdx.x;
  const int cpx = gridDim.x >> 3;
  id = (id & 7) * cpx + (id >> 3);
  const int bm = (id >> 5) << 7;
  const int bn = (id & 31) << 7;

  const int arow = tid >> 4;
  const int acol = (tid & 15) << 2;
  const int brow = tid >> 3;
  const int bcol = (tid & 7) << 3;

  const int lrow = lane & 15;
  const int lgo = (lane >> 4) << 3;

  f32x4 acc[4][4] = {};

  for (int k0 = 0; k0 < K_TOT; k0 += 64) {
#pragma unroll
    for (int r = 0; r < 8; ++r) {
      const int row = arow + r * 16;
      const float4 v = *reinterpret_cast<const float4*>(
          x + (size_t)(bm + row) * K_TOT + k0 + acol);
      ushort4 bvec;
      bvec.x = f2bf(v.x); bvec.y = f2bf(v.y); bvec.z = f2bf(v.z); bvec.w = f2bf(v.w);
      *reinterpret_cast<ushort4*>(&Asl[row * LDS_STRIDE + acol]) = bvec;
    }
    if (PREPPED) {
#pragma unroll
      for (int r = 0; r < 4; ++r) {
        const int row = brow + r * 32;
        const s16x8 v = *reinterpret_cast<const s16x8*>(
            wb + (size_t)(bn + row) * K_TOT + k0 + bcol);
        *reinterpret_cast<s16x8*>(&Bsl[row * LDS_STRIDE + bcol]) = v;
      }
    } else {
#pragma unroll
      for (int r = 0; r < 8; ++r) {
        const int row = arow + r * 16;
        const float4 v = *reinterpret_cast<const float4*>(
            wf + (size_t)(bn + row) * K_TOT + k0 + acol);
        ushort4 bvec;
        bvec.x = 0; bvec.y = 0; bvec.z = 0; bvec.w = 0;
        if (mask8[((bn + row) >> 5) * MASK_DIM + ((k0 + acol) >> 5)]) {
          bvec.x = f2bf(v.x); bvec.y = f2bf(v.y); bvec.z = f2bf(v.z); bvec.w = f2bf(v.w);
        }
        *reinterpret_cast<ushort4*>(&Bsl[row * LDS_STRIDE + acol]) = bvec;
      }
    }
    __syncthreads();

#pragma unroll
    for (int ks = 0; ks < 2; ++ks) {
      s16x8 af[4], bfv[4];
#pragma unroll
      for (int m = 0; m < 4; ++m)
        af[m] = *reinterpret_cast<const s16x8*>(
            &Asl[(wr * 64 + m * 16 + lrow) * LDS_STRIDE + ks * 32 + lgo]);
#pragma unroll
      for (int n = 0; n < 4; ++n)
        bfv[n] = *reinterpret_cast<const s16x8*>(
            &Bsl[(wcn * 64 + n * 16 + lrow) * LDS_STRIDE + ks * 32 + lgo]);
#pragma unroll
      for (int m = 0; m < 4; ++m)
#pragma unroll
        for (int n = 0; n < 4; ++n)
          acc[m][n] = __builtin_amdgcn_mfma_f32_16x16x32_bf16(af[m], bfv[n],
                                                              acc[m][n], 0, 0, 0);
    }
    __syncthreads();
  }

#pragma unroll
  for (int n = 0; n < 4; ++n) {
    const int gcol = bn + wcn * 64 + n * 16 + lrow;
    const float bv = bias[gcol];
#pragma unroll
    for (int m = 0; m < 4; ++m) {
      const int grow = bm + wr * 64 + m * 16 + ((lane >> 4) << 2);
#pragma unroll
      for (int j = 0; j < 4; ++j) {
        out[(size_t)(grow + j) * N_TOT + gcol] = 2.0f * acc[m][n][j] + bv;
      }
    }
  }
}

extern "C" void kernel_launch(void* const* d_in, const int* in_sizes, int n_in,
                              void* d_out, int out_size, void* d_ws, size_t ws_size,
                              hipStream_t stream) {
  const float* x = (const float*)d_in[0];
  const float* w = (const float*)d_in[1];
  const float* bias = (const float*)d_in[2];
  const unsigned char* mask_raw = (const unsigned char*)d_in[3];
  float* out = (float*)d_out;

  unsigned char* ws_mask = (unsigned char*)d_ws;            // 16 KiB mask8
  u16* wb = (u16*)((char*)d_ws + 65536);                    // 32 MiB bf16 W
  u16* xb = (u16*)((char*)d_ws + 65536 +
                   (size_t)N_TOT * K_TOT * sizeof(u16));    // 128 MiB bf16 x
  const size_t need_w = 65536 + (size_t)N_TOT * K_TOT * sizeof(u16);
  const size_t need_full = need_w + (size_t)M_TOT * K_TOT * sizeof(u16);

  prep_mask_kernel<<<1, 256, 0, stream>>>(mask_raw, ws_mask);

  if (ws_size >= need_full) {
    prep_w_swz_kernel<<<(N_TOT * (K_TOT / 8)) / 256, 256, 0, stream>>>(w, ws_mask, wb);
    prep_x_swz_kernel<<<(M_TOT * (K_TOT / 8)) / 256, 256, 0, stream>>>(x, xb);
    hipFuncSetAttribute(reinterpret_cast<const void*>(gemm_8p_kernel),
                        hipFuncAttributeMaxDynamicSharedMemorySize, 131072);
    gemm_8p_kernel<<<(M_TOT / 256) * (N_TOT / 256), 512, 131072, stream>>>(
        xb, wb, bias, out);
  } else if (ws_size >= need_w) {
    prep_w_kernel<<<(N_TOT * K_TOT) / (256 * 4), 256, 0, stream>>>(w, ws_mask, wb);
    gemm_kernel<true><<<(M_TOT / 128) * (N_TOT / 128), 256, 0, stream>>>(
        x, wb, nullptr, nullptr, bias, out);
  } else {
    gemm_kernel<false><<<(M_TOT / 128) * (N_TOT / 128), 256, 0, stream>>>(
        x, nullptr, w, ws_mask, bias, out);
  }
}